// Round 6
// baseline (1796.262 us; speedup 1.0000x reference)
//
#include <hip/hip_runtime.h>
#include <cstdint>

// ---------- types ----------
typedef __bf16 bf16x8 __attribute__((ext_vector_type(8)));
typedef float f32x4 __attribute__((ext_vector_type(4)));
typedef unsigned int u32x4 __attribute__((ext_vector_type(4)));
typedef unsigned int u32x2 __attribute__((ext_vector_type(2)));
typedef unsigned short u16x4 __attribute__((ext_vector_type(4)));

#define D_MODEL 1024
#define SEQ     2048
#define NBATCH  4
#define NHEAD   16
#define HDIM    64
#define NTOK    (NBATCH * SEQ)   // 8192
#define QSCALE  0.18033688011112042f   // 0.125 * log2(e)

__device__ __forceinline__ unsigned short f2bf(float f) {
  unsigned int u = __builtin_bit_cast(unsigned int, f);
  u += 0x7FFFu + ((u >> 16) & 1u);           // round-to-nearest-even
  return (unsigned short)(u >> 16);
}

__device__ __forceinline__ float bf2f(unsigned short s) {
  return __builtin_bit_cast(float, (unsigned int)s << 16);
}

__device__ __forceinline__ bf16x8 load8bf(const unsigned short* p) {
  return __builtin_bit_cast(bf16x8, *(const u32x4*)p);
}

__device__ __forceinline__ f32x4 mfma16(bf16x8 a, bf16x8 b, f32x4 c) {
  return __builtin_amdgcn_mfma_f32_16x16x32_bf16(a, b, c, 0, 0, 0);
}

// async global->LDS, 16B per lane; LDS dest must be waveBase + lane*16
__device__ __forceinline__ void gload16(const unsigned short* g, unsigned short* l) {
  __builtin_amdgcn_global_load_lds((__attribute__((address_space(1))) void*)g,
                                   (__attribute__((address_space(3))) void*)l, 16, 0, 0);
}

// ---------- batched transposing weight cast: out[n][k] = bf16(in[k][n]) ----------
__global__ __launch_bounds__(256) void tcast_all(const float* __restrict__ wq,
                                                 const float* __restrict__ wk,
                                                 const float* __restrict__ wv,
                                                 const float* __restrict__ wo,
                                                 const float* __restrict__ w1,
                                                 const float* __restrict__ w2,
                                                 unsigned short* __restrict__ wqkv_t,
                                                 unsigned short* __restrict__ wo_t,
                                                 unsigned short* __restrict__ w1_t,
                                                 unsigned short* __restrict__ w2_t) {
  const int id = blockIdx.x;
  const float* in; unsigned short* out; int K, N, k0, n0;
  if (id < 4096) {             // wq/wk/wv/wo: 1024x1024 each
    const int seg = id >> 10, r = id & 1023;
    in  = seg == 0 ? wq : seg == 1 ? wk : seg == 2 ? wv : wo;
    out = seg == 3 ? wo_t : wqkv_t + (size_t)seg * 1024 * 1024;
    K = 1024; N = 1024; n0 = (r & 31) * 32; k0 = (r >> 5) * 32;
  } else if (id < 8192) {      // w1: K=1024 -> N=4096
    const int r = id - 4096;
    in = w1; out = w1_t; K = 1024; N = 4096;
    n0 = (r & 127) * 32; k0 = (r >> 7) * 32;
  } else {                     // w2: K=4096 -> N=1024
    const int r = id - 8192;
    in = w2; out = w2_t; K = 4096; N = 1024;
    n0 = (r & 31) * 32; k0 = (r >> 5) * 32;
  }
  __shared__ float tile[32][33];
  const int tx = threadIdx.x & 31, ty = threadIdx.x >> 5;
  #pragma unroll
  for (int j = 0; j < 4; ++j)
    tile[ty + 8 * j][tx] = in[(size_t)(k0 + ty + 8 * j) * N + n0 + tx];
  __syncthreads();
  #pragma unroll
  for (int j = 0; j < 4; ++j)
    out[(size_t)(n0 + ty + 8 * j) * K + k0 + tx] = f2bf(tile[tx][ty + 8 * j]);
}

// ---------- layernorm (D=1024): FPIN=1 fp32 input, else bf16 input ----------
template <int FPIN>
__global__ __launch_bounds__(256) void ln_kernel(const void* __restrict__ xin,
                                                 const float* __restrict__ g,
                                                 const float* __restrict__ bb,
                                                 unsigned short* __restrict__ out) {
  const int row = blockIdx.x, tid = threadIdx.x;
  float4 xv;
  if (FPIN) {
    xv = ((const float4*)((const float*)xin + (size_t)row * D_MODEL))[tid];
  } else {
    const u16x4 bv4 = ((const u16x4*)((const unsigned short*)xin + (size_t)row * D_MODEL))[tid];
    xv.x = bf2f(bv4.x); xv.y = bf2f(bv4.y); xv.z = bf2f(bv4.z); xv.w = bf2f(bv4.w);
  }
  float s  = xv.x + xv.y + xv.z + xv.w;
  float ss = xv.x * xv.x + xv.y * xv.y + xv.z * xv.z + xv.w * xv.w;
  #pragma unroll
  for (int off = 1; off < 64; off <<= 1) { s += __shfl_xor(s, off); ss += __shfl_xor(ss, off); }
  __shared__ float red[8];
  const int wave = tid >> 6, lane = tid & 63;
  if (lane == 0) { red[wave] = s; red[4 + wave] = ss; }
  __syncthreads();
  s  = red[0] + red[1] + red[2] + red[3];
  ss = red[4] + red[5] + red[6] + red[7];
  const float mu   = s * (1.0f / D_MODEL);
  const float var  = ss * (1.0f / D_MODEL) - mu * mu;
  const float rstd = rsqrtf(var + 1e-5f);
  const float4 gv = ((const float4*)g)[tid];
  const float4 bv = ((const float4*)bb)[tid];
  u16x4 o;
  o.x = f2bf((xv.x - mu) * rstd * gv.x + bv.x);
  o.y = f2bf((xv.y - mu) * rstd * gv.y + bv.y);
  o.z = f2bf((xv.z - mu) * rstd * gv.z + bv.z);
  o.w = f2bf((xv.w - mu) * rstd * gv.w + bv.w);
  *(u16x4*)(out + (size_t)row * D_MODEL + tid * 4) = o;
}

// ---------- GEMM (legacy 128x128, used for WO): C = A * Bt^T ----------
template <bool BIAS, bool RELU, int RES, bool OBF>
__global__ __launch_bounds__(256) void gemm_bt(const unsigned short* __restrict__ A,
                                               const unsigned short* __restrict__ Bt,
                                               const float* __restrict__ bias,
                                               const void* __restrict__ res,
                                               void* __restrict__ out,
                                               int M, int N, int K) {
  __shared__ __align__(16) unsigned short As[128 * 64];
  __shared__ __align__(16) unsigned short Bs[128 * 64];
  const int tid  = threadIdx.x;
  const int lin = blockIdx.y * gridDim.x + blockIdx.x;   // gridDim.y == 64 always
  const int xcd = lin & 7, idx = lin >> 3;
  const int by = xcd * 8 + (idx & 7);
  const int bx = idx >> 3;
  const int row0 = by * 128, col0 = bx * 128;
  const int wave = tid >> 6, lane = tid & 63;
  const int wm = wave >> 1, wn = wave & 1;
  const int l15 = lane & 15, quad = lane >> 4;
  f32x4 acc[4][4] = {};

  const int tr = tid >> 3;                        // base row 0..31
  const int tc = (tid & 7) ^ (tr & 7);            // swizzled source chunk
  const unsigned short* gA = A  + (size_t)(row0 + tr) * K + tc * 8;
  const unsigned short* gB = Bt + (size_t)(col0 + tr) * K + tc * 8;

  const int rowA = (wm * 64 + l15) * 64;
  const int rowB = (wn * 64 + l15) * 64;
  const int swz0 = (quad ^ (l15 & 7)) * 8;
  const int swz1 = ((4 + quad) ^ (l15 & 7)) * 8;

  for (int k0 = 0; k0 < K; k0 += 64) {
    #pragma unroll
    for (int i = 0; i < 4; ++i) {
      gload16(gA + (size_t)(i * 32) * K + k0, As + (i * 256 + tid) * 8);
      gload16(gB + (size_t)(i * 32) * K + k0, Bs + (i * 256 + tid) * 8);
    }
    __syncthreads();
    #pragma unroll
    for (int kf = 0; kf < 2; ++kf) {
      const int swz = kf ? swz1 : swz0;
      bf16x8 af[4], bfr[4];
      #pragma unroll
      for (int t = 0; t < 4; ++t) {
        af[t]  = load8bf(As + rowA + t * 1024 + swz);
        bfr[t] = load8bf(Bs + rowB + t * 1024 + swz);
      }
      #pragma unroll
      for (int i = 0; i < 4; ++i)
        #pragma unroll
        for (int j = 0; j < 4; ++j)
          acc[i][j] = mfma16(af[i], bfr[j], acc[i][j]);
    }
    __syncthreads();
  }

  const size_t rbase = (size_t)row0 + wm * 64 + quad * 4;
  const int cbase = col0 + wn * 64 + l15;
  #pragma unroll
  for (int i = 0; i < 4; ++i) {
    #pragma unroll
    for (int j = 0; j < 4; ++j) {
      const int col = cbase + j * 16;
      const float bval = BIAS ? bias[col] : 0.0f;
      #pragma unroll
      for (int r = 0; r < 4; ++r) {
        const size_t row = rbase + i * 16 + r;
        float v = acc[i][j][r];
        if (BIAS) v += bval;
        if (RELU) v = fmaxf(v, 0.0f);
        if (RES == 1) v += ((const float*)res)[row * N + col];
        if (RES == 2) v += bf2f(((const unsigned short*)res)[row * N + col]);
        if (OBF)  ((unsigned short*)out)[row * N + col] = f2bf(v);
        else      ((float*)out)[row * N + col] = v;
      }
    }
  }
}

// ---------- BK=32 staging: one 128-row x 32-col half (8KB), 1 gload/thread ----------
// Paired-row lines: LDS line L (128B) holds rows 2L,2L+1; chunk p at line L holds
// global (row = 2L+(c>>2), colchunk = c&3) with c = p ^ (L&7). LDS dest stays
// linear (gload_lds constraint); the swizzle lives in the global source address.
__device__ __forceinline__ void stage32(const unsigned short* __restrict__ src,
                                        unsigned short* dst, int ld, int k0,
                                        int h, int tid) {
  const int L = tid >> 3;               // line within half (0..63)
  const int p = tid & 7;
  const int c = p ^ (L & 7);
  const int row = h * 128 + L * 2 + (c >> 2);
  gload16(src + (size_t)row * ld + k0 + (c & 3) * 8, dst + h * 4096 + tid * 8);
}

// read one 16-row x 32-col fragment: rows r0+l15, k-dims quad*8..+8
// chunk = ((row&1)*4 + quad) ^ (line&7). Bank check: any 16 consecutive lanes
// hit all 8 chunks exactly twice -> 2 lanes/bank (free, m136).
__device__ __forceinline__ bf16x8 frag32(const unsigned short* tile, int r0,
                                         int l15, int quad) {
  const int row = r0 + l15;
  const int L = row >> 1;
  const int p = ((row & 1) * 4 + quad) ^ (L & 7);
  return load8bf(tile + L * 64 + p * 8);
}

// ---------- 256x256 GEMM, BK=32, 64KB LDS -> 2 blocks/CU ----------
// Same 8-wave (2Mx4N) layout, acc[8][4]. Occupancy-2 provides the m114
// cross-block MFMA/LDS overlap that the 1-block/CU schedule couldn't express:
// the co-resident block's waves share no barriers with ours, so its ds_read/
// stage traffic fills the LDS pipe while our MFMA cluster runs, and vice versa.
// Prefetch: A(t+1) staged in P1 (other buffer), B(t+2) staged in P2 (current
// buffer's B, whose reads completed before the P1-end barrier). Counted
// vmcnt(2) at tile end: drains A(t+1) (and B(t+1), issued earlier), leaves
// B(t+2) in flight -> tile t+1 fully resident, never a full drain mid-loop.
template <bool BIAS, bool RELU, int RES, bool OBF, bool QKV, bool SPLITK>
__global__ __launch_bounds__(512, 4) void gemm256(const unsigned short* __restrict__ A,
                                                  const unsigned short* __restrict__ Bt,
                                                  const float* __restrict__ bias,
                                                  const void* __restrict__ res,
                                                  void* __restrict__ out,
                                                  unsigned short* __restrict__ qb,
                                                  unsigned short* __restrict__ kp,
                                                  unsigned short* __restrict__ vt,
                                                  int M, int N, int K, int lda, int ldb) {
  __shared__ __align__(16) unsigned short lds[2][16384];  // [buf][ A 8192sh | B 8192sh ]
  const int tid = threadIdx.x;
  const int lin = blockIdx.y * gridDim.x + blockIdx.x;    // gridDim.y == 32 (M = 8192)
  const int xcd = lin & 7, idx = lin >> 3;
  const int by = xcd * 4 + (idx & 3);
  const int bxr = idx >> 2;
  const int ks  = SPLITK ? (bxr >> 2) : 0;
  const int bx  = SPLITK ? (bxr & 3) : bxr;
  const int row0 = by * 256, col0 = bx * 256;
  const int koff = SPLITK ? ks * K : 0;                   // K = half-depth under split
  const int wave = tid >> 6, lane = tid & 63;
  const int wm = wave >> 2, wn = wave & 3;                // 2 x 4 waves, 128x64 each
  const int l15 = lane & 15, quad = lane >> 4;

  const unsigned short* gA = A  + (size_t)row0 * lda + koff;
  const unsigned short* gB = Bt + (size_t)col0 * ldb + koff;

  unsigned short* As0 = &lds[0][0];
  unsigned short* Bs0 = &lds[0][8192];
  unsigned short* As1 = &lds[1][0];
  unsigned short* Bs1 = &lds[1][8192];

  f32x4 acc[8][4] = {};
  const int KT = K >> 5;

  // ---- prologue: tile0 (A+B) -> buf0; tile1 B -> buf1 (stays in flight) ----
  stage32(gA, As0, lda, 0, 0, tid);
  stage32(gA, As0, lda, 0, 1, tid);
  stage32(gB, Bs0, ldb, 0, 0, tid);
  stage32(gB, Bs0, ldb, 0, 1, tid);
  if (KT > 1) {
    stage32(gB, Bs1, ldb, 32, 0, tid);
    stage32(gB, Bs1, ldb, 32, 1, tid);
    asm volatile("s_waitcnt vmcnt(2)" ::: "memory");
  } else {
    asm volatile("s_waitcnt vmcnt(0)" ::: "memory");
  }
  asm volatile("s_barrier" ::: "memory");

  for (int t = 0; t < KT; ++t) {
    unsigned short* As  = (t & 1) ? As1 : As0;
    unsigned short* Bs  = (t & 1) ? Bs1 : Bs0;
    unsigned short* Asn = (t & 1) ? As0 : As1;
    const int k1 = (t + 1) << 5, k2 = (t + 2) << 5;
    bf16x8 a[4], b[4];

    // ===== P1: read a[0..3] + b[0..3]; stage A(t+1); MFMA top half =====
    #pragma unroll
    for (int i = 0; i < 4; ++i) a[i] = frag32(As, wm * 128 + i * 16, l15, quad);
    #pragma unroll
    for (int j = 0; j < 4; ++j) b[j] = frag32(Bs, wn * 64 + j * 16, l15, quad);
    if (t + 1 < KT) {
      stage32(gA, Asn, lda, k1, 0, tid);
      stage32(gA, Asn, lda, k1, 1, tid);
    }
    __builtin_amdgcn_s_setprio(1);
    #pragma unroll
    for (int i = 0; i < 4; ++i)
      #pragma unroll
      for (int j = 0; j < 4; ++j)
        acc[i][j] = mfma16(a[i], b[j], acc[i][j]);
    __builtin_amdgcn_s_setprio(0);
    __builtin_amdgcn_sched_barrier(0);
    asm volatile("s_barrier" ::: "memory");   // all waves' B reads of tile t done

    // ===== P2: read a[4..7]; stage B(t+2) (cur buf B, consumed); MFMA bottom =====
    #pragma unroll
    for (int i = 0; i < 4; ++i) a[i] = frag32(As, wm * 128 + 64 + i * 16, l15, quad);
    if (t + 2 < KT) {
      stage32(gB, Bs, ldb, k2, 0, tid);
      stage32(gB, Bs, ldb, k2, 1, tid);
    }
    __builtin_amdgcn_s_setprio(1);
    #pragma unroll
    for (int i = 0; i < 4; ++i)
      #pragma unroll
      for (int j = 0; j < 4; ++j)
        acc[4 + i][j] = mfma16(a[i], b[j], acc[4 + i][j]);
    __builtin_amdgcn_s_setprio(0);
    __builtin_amdgcn_sched_barrier(0);
    if (t + 2 < KT) asm volatile("s_waitcnt vmcnt(2)" ::: "memory");
    else            asm volatile("s_waitcnt vmcnt(0)" ::: "memory");
    asm volatile("s_barrier" ::: "memory");
  }

  // ---- epilogue ----
  const size_t rbase = (size_t)row0 + wm * 128 + quad * 4;
  const int cbase = col0 + wn * 64 + l15;
  if (QKV) {
    const int sec = col0 >> 10;           // block-uniform (256 | 1024): 0=Q, 1=K, 2=V
    #pragma unroll
    for (int i = 0; i < 8; ++i) {
      #pragma unroll
      for (int j = 0; j < 4; ++j) {
        const int col = cbase + j * 16;
        if (sec == 0) {
          #pragma unroll
          for (int r = 0; r < 4; ++r) {
            const size_t row = rbase + i * 16 + r;
            qb[row * 1024 + col] = f2bf(acc[i][j][r] * QSCALE);
          }
        } else if (sec == 1) {
          const int c2 = col - 1024, hh = c2 >> 6, d = c2 & 63;
          #pragma unroll
          for (int r = 0; r < 4; ++r) {
            const size_t row = rbase + i * 16 + r;
            const int bb = (int)(row >> 11), tt = (int)(row & 2047);
            kp[(((size_t)(bb * 16 + hh)) * SEQ + tt) * 64 + d] = f2bf(acc[i][j][r]);
          }
        } else {
          const int c2 = col - 2048, hh = c2 >> 6, d = c2 & 63;
          const size_t t0 = rbase + i * 16;
          const int bb = (int)(t0 >> 11);
          u16x4 pk;
          #pragma unroll
          for (int r = 0; r < 4; ++r) pk[r] = f2bf(acc[i][j][r]);
          *(u16x4*)(vt + ((size_t)(bb * 16 + hh) * 64 + d) * SEQ + (t0 & 2047)) = pk;
        }
      }
    }
  } else if (SPLITK) {
    float* po = (float*)out + (size_t)ks * M * N;
    #pragma unroll
    for (int i = 0; i < 8; ++i) {
      #pragma unroll
      for (int j = 0; j < 4; ++j) {
        const int col = cbase + j * 16;
        #pragma unroll
        for (int r = 0; r < 4; ++r) {
          const size_t row = rbase + i * 16 + r;
          po[row * N + col] = acc[i][j][r];
        }
      }
    }
  } else {
    #pragma unroll
    for (int i = 0; i < 8; ++i) {
      #pragma unroll
      for (int j = 0; j < 4; ++j) {
        const int col = cbase + j * 16;
        const float bval = BIAS ? bias[col] : 0.0f;
        #pragma unroll
        for (int r = 0; r < 4; ++r) {
          const size_t row = rbase + i * 16 + r;
          float v = acc[i][j][r];
          if (BIAS) v += bval;
          if (RELU) v = fmaxf(v, 0.0f);
          if (RES == 1) v += ((const float*)res)[row * N + col];
          if (RES == 2) v += bf2f(((const unsigned short*)res)[row * N + col]);
          if (OBF)  ((unsigned short*)out)[row * N + col] = f2bf(v);
          else      ((float*)out)[row * N + col] = v;
        }
      }
    }
  }
  (void)M;
}

// ---------- split-K reduce: out = p0 + p1 + b2 + bf16(x1b), fp32 out ----------
__global__ __launch_bounds__(256) void ffn2_reduce(const float* __restrict__ p0,
                                                   const float* __restrict__ p1,
                                                   const float* __restrict__ b2,
                                                   const unsigned short* __restrict__ x1b,
                                                   float* __restrict__ out) {
  const size_t i4 = (size_t)blockIdx.x * 256 + threadIdx.x;   // float4 index
  const float4 a = ((const float4*)p0)[i4];
  const float4 b = ((const float4*)p1)[i4];
  const float4 bi = ((const float4*)b2)[i4 & 255];            // 1024/4 = 256 groups/row
  const u16x4 rv = ((const u16x4*)x1b)[i4];
  float4 o;
  o.x = a.x + b.x + bi.x + bf2f(rv.x);
  o.y = a.y + b.y + bi.y + bf2f(rv.y);
  o.z = a.z + b.z + bi.z + bf2f(rv.z);
  o.w = a.w + b.w + bi.w + bf2f(rv.w);
  ((float4*)out)[i4] = o;
}

// ---------- fused causal attention v5 ----------
__global__ __launch_bounds__(256) void attn5(const unsigned short* __restrict__ qb,
                                             const unsigned short* __restrict__ kp,
                                             const unsigned short* __restrict__ vt,
                                             unsigned short* __restrict__ attnb) {
  const int lin = (blockIdx.z * 16 + blockIdx.y) * 8 + blockIdx.x;  // 512 blocks
  const int xcd = lin & 7, idx = lin >> 3;
  const int bh = xcd * 8 + (idx >> 3);
  const int xb = idx & 7;
  const int b = bh >> 4, h = bh & 15;
  const int tid = threadIdx.x, wave = tid >> 6, lane = tid & 63;
  const int l15 = lane & 15, quad = lane >> 4;
  const size_t tokbase = (size_t)b * SEQ;

  __shared__ __align__(16) unsigned short ks[64 * 64];       // [key][dim], chunk-swizzled
  __shared__ __align__(16) unsigned short vts[64 * 64];      // [dim][key], chunk-swizzled
  __shared__ __align__(16) unsigned short plds[4][32 * 64];  // per-wave P[q][key], swizzled

  const unsigned short* kbase = kp + (size_t)bh * SEQ * HDIM;
  const unsigned short* vbase = vt + (size_t)bh * HDIM * SEQ;

  for (int half = 0; half < 2; ++half) {
    const int qblk = (half == 0) ? (15 - xb) : xb;
    const int qw0 = qblk * 128 + wave * 32;

    bf16x8 qf[2][2];   // [qf][kf]: rows qw0+qf*16+l15, dims kf*32+quad*8..+8
    #pragma unroll
    for (int qfi = 0; qfi < 2; ++qfi)
      #pragma unroll
      for (int kf = 0; kf < 2; ++kf)
        qf[qfi][kf] = load8bf(qb + (tokbase + qw0 + qfi * 16 + l15) * 1024
                              + h * HDIM + kf * 32 + quad * 8);

    f32x4 o[2][4] = {};
    float lsum[2] = {0.0f, 0.0f};

    const int ntiles = qblk * 2 + 2;
    for (int kt = 0; kt < ntiles; ++kt) {
      const int k0 = kt * 64;
      __syncthreads();                       // previous tile fully consumed
      #pragma unroll
      for (int i = 0; i < 2; ++i) {          // stage K tile (8KB)
        const int cid = i * 256 + tid;
        const int r = cid >> 3, p = cid & 7, c = p ^ (r & 7);
        gload16(kbase + (size_t)(k0 + r) * HDIM + c * 8, ks + cid * 8);
      }
      #pragma unroll
      for (int i = 0; i < 2; ++i) {          // stage V^T tile (8KB)
        const int cid = i * 256 + tid;
        const int d = cid >> 3, p = cid & 7, c = p ^ (d & 7);
        gload16(vbase + (size_t)d * SEQ + k0 + c * 8, vts + cid * 8);
      }
      __syncthreads();                       // vmcnt drain -> staged data visible
      if (k0 <= qw0 + 31) {
        // ---- QK^T (swapped): s[keyf][qfi] ----
        f32x4 s[4][2] = {};
        #pragma unroll
        for (int kf = 0; kf < 2; ++kf)
          #pragma unroll
          for (int keyf = 0; keyf < 4; ++keyf) {
            const int row = keyf * 16 + l15;
            const int p = (kf * 4 + quad) ^ (row & 7);
            const bf16x8 kfr = load8bf(ks + row * 64 + p * 8);
            s[keyf][0] = mfma16(kfr, qf[0][kf], s[keyf][0]);
            s[keyf][1] = mfma16(kfr, qf[1][kf], s[keyf][1]);
          }
        // ---- fixed-max softmax + packed P store ----
        #pragma unroll
        for (int qfi = 0; qfi < 2; ++qfi) {
          const int q = qw0 + qfi * 16 + l15;
          const int qloc = qfi * 16 + l15;
          #pragma unroll
          for (int keyf = 0; keyf < 4; ++keyf) {
            unsigned int pw[4];
            #pragma unroll
            for (int r = 0; r < 4; ++r) {
              const int key = k0 + keyf * 16 + quad * 4 + r;
              float p = __builtin_amdgcn_exp2f(s[keyf][qfi][r]);
              p = (key > q) ? 0.0f : p;
              pw[r] = __builtin_bit_cast(unsigned int, p);
              lsum[qfi] += __builtin_bit_cast(float, pw[r] & 0xFFFF0000u);
            }
            u32x2 packed;
            packed.x = (pw[0] >> 16) | (pw[1] & 0xFFFF0000u);
            packed.y = (pw[2] >> 16) | (pw[3] & 0xFFFF0000u);
            const int slot = (keyf * 4 + quad) ^ ((l15 & 7) << 1);
            *(u32x2*)(&plds[wave][qloc * 64 + slot * 4]) = packed;
          }
        }
        __builtin_amdgcn_s_waitcnt(0);       // wave-local plds writes -> reads
        // ---- PV: A=P (m=q,k=key), B=V^T (n=d,k=key) ----
        #pragma unroll
        for (int kf = 0; kf < 2; ++kf) {
          bf16x8 pa[2];
          #pragma unroll
          for (int mf = 0; mf < 2; ++mf) {
            const int lq = mf * 16 + l15;
            const int c = (kf * 4 + quad) ^ (l15 & 7);
            pa[mf] = load8bf(&plds[wave][lq * 64 + c * 8]);
          }
          #pragma unroll
          for (int df = 0; df < 4; ++df) {
            const int row = df * 16 + l15;
            const int p = (kf * 4 + quad) ^ (row & 7);
            const bf16x8 vb = load8bf(vts + row * 64 + p * 8);
            o[0][df] = mfma16(pa[0], vb, o[0][df]);
            o[1][df] = mfma16(pa[1], vb, o[1][df]);
          }
        }
      }
    }
    // ---- normalize + write ----
    #pragma unroll
    for (int mf = 0; mf < 2; ++mf) {
      float l = lsum[mf];
      l += __shfl_xor(l, 16);
      l += __shfl_xor(l, 32);
      const float rl = 1.0f / l;
      #pragma unroll
      for (int r = 0; r < 4; ++r) {
        const float rv = __shfl(rl, quad * 4 + r);   // lane holding q=..+quad*4+r
        const size_t row = tokbase + qw0 + mf * 16 + quad * 4 + r;
        #pragma unroll
        for (int df = 0; df < 4; ++df)
          attnb[row * D_MODEL + h * HDIM + df * 16 + l15] = f2bf(o[mf][df][r] * rv);
      }
    }
  }
}

// ---------- host ----------
extern "C" void kernel_launch(void* const* d_in, const int* in_sizes, int n_in,
                              void* d_out, int out_size, void* d_ws, size_t ws_size,
                              hipStream_t stream) {
  const float* x    = (const float*)d_in[0];
  const float* wq   = (const float*)d_in[1];
  const float* wk   = (const float*)d_in[2];
  const float* wv   = (const float*)d_in[3];
  const float* wo   = (const float*)d_in[4];
  const float* bo   = (const float*)d_in[5];
  const float* w1   = (const float*)d_in[6];
  const float* b1   = (const float*)d_in[7];
  const float* w2   = (const float*)d_in[8];
  const float* b2   = (const float*)d_in[9];
  const float* g1   = (const float*)d_in[10];
  const float* bl1  = (const float*)d_in[11];
  const float* g2   = (const float*)d_in[12];
  const float* bl2  = (const float*)d_in[13];
  float* out = (float*)d_out;

  char* ws = (char*)d_ws;
  size_t off = 0;
  auto alloc = [&](size_t bytes) { char* p = ws + off; off += (bytes + 255) & ~(size_t)255; return p; };
  unsigned short* wqkv_t = (unsigned short*)alloc((size_t)3072 * 1024 * 2);
  unsigned short* wo_t   = (unsigned short*)alloc((size_t)1024 * 1024 * 2);
  unsigned short* w1_t   = (unsigned short*)alloc((size_t)4096 * 1024 * 2);
  unsigned short* w2_t   = (unsigned short*)alloc((size_t)1024 * 4096 * 2);
  unsigned short* h1     = (unsigned short*)alloc((size_t)NTOK * 1024 * 2);
  unsigned short* kpb    = (unsigned short*)alloc((size_t)NTOK * 1024 * 2);  // K packed
  unsigned short* vtb    = (unsigned short*)alloc((size_t)NTOK * 1024 * 2);  // V^T packed
  unsigned short* attnb  = (unsigned short*)alloc((size_t)NTOK * 1024 * 2);
  unsigned short* h2     = (unsigned short*)alloc((size_t)NTOK * 1024 * 2);
  unsigned short* ffn1   = (unsigned short*)alloc((size_t)NTOK * 4096 * 2);
  // qb aliases attnb; x1b aliases h1 (dead after QKV GEMM).
  unsigned short* qb  = attnb;
  unsigned short* x1b = h1;
  // FFN2 split-K fp32 partials (2 x 32MB) alias kpb..h2 (all dead after FFN1):
  // kpb,vtb,attnb,h2 are 4 contiguous 16MB regions = exactly 64MB.
  float* part = (float*)kpb;

  tcast_all<<<12288, 256, 0, stream>>>(wq, wk, wv, wo, w1, w2,
                                       wqkv_t, wo_t, w1_t, w2_t);
  ln_kernel<1><<<NTOK, 256, 0, stream>>>(x, g1, bl1, h1);
  // fused QKV: 12x32 = 384 blocks (0.75 of 512-slot capacity at 2 blocks/CU)
  gemm256<false, false, 0, true, true, false><<<dim3(12, 32), 512, 0, stream>>>(
      h1, wqkv_t, nullptr, nullptr, nullptr, qb, kpb, vtb, NTOK, 3072, 1024, 1024, 1024);
  attn5<<<dim3(SEQ / 256, NHEAD, NBATCH), 256, 0, stream>>>(qb, kpb, vtb, attnb);
  // x1 = x + attn @ wo + bo  -> bf16 x1b   (legacy 128^2)
  gemm_bt<true, false, 1, true><<<dim3(8, 64), 256, 0, stream>>>(
      attnb, wo_t, bo, x, x1b, NTOK, 1024, 1024);
  ln_kernel<0><<<NTOK, 256, 0, stream>>>(x1b, g2, bl2, h2);
  // FFN1: 16x32 = 512 blocks = exactly fills 2-blocks/CU capacity
  gemm256<true, true, 0, true, false, false><<<dim3(16, 32), 512, 0, stream>>>(
      h2, w1_t, b1, nullptr, ffn1, nullptr, nullptr, nullptr, NTOK, 4096, 1024, 1024, 1024);
  // FFN2 (split-K=2): 8x32 = 256 blocks
  gemm256<false, false, 0, false, false, true><<<dim3(8, 32), 512, 0, stream>>>(
      ffn1, w2_t, nullptr, nullptr, part, nullptr, nullptr, nullptr,
      NTOK, 1024, 2048, 4096, 4096);
  // out = part0 + part1 + b2 + x1b (fp32 out)
  ffn2_reduce<<<NTOK * 1024 / 4 / 256, 256, 0, stream>>>(
      part, part + (size_t)NTOK * 1024, b2, x1b, out);
  (void)in_sizes; (void)n_in; (void)out_size; (void)ws_size;
}

// Round 7
// 472.163 us; speedup vs baseline: 3.8043x; 3.8043x over previous
//
#include <hip/hip_runtime.h>
#include <cstdint>

// ---------- types ----------
typedef __bf16 bf16x8 __attribute__((ext_vector_type(8)));
typedef float f32x4 __attribute__((ext_vector_type(4)));
typedef unsigned int u32x4 __attribute__((ext_vector_type(4)));
typedef unsigned int u32x2 __attribute__((ext_vector_type(2)));
typedef unsigned short u16x4 __attribute__((ext_vector_type(4)));

#define D_MODEL 1024
#define SEQ     2048
#define NBATCH  4
#define NHEAD   16
#define HDIM    64
#define NTOK    (NBATCH * SEQ)   // 8192
#define QSCALE  0.18033688011112042f   // 0.125 * log2(e)

__device__ __forceinline__ unsigned short f2bf(float f) {
  unsigned int u = __builtin_bit_cast(unsigned int, f);
  u += 0x7FFFu + ((u >> 16) & 1u);           // round-to-nearest-even
  return (unsigned short)(u >> 16);
}

__device__ __forceinline__ float bf2f(unsigned short s) {
  return __builtin_bit_cast(float, (unsigned int)s << 16);
}

__device__ __forceinline__ bf16x8 load8bf(const unsigned short* p) {
  return __builtin_bit_cast(bf16x8, *(const u32x4*)p);
}

__device__ __forceinline__ f32x4 mfma16(bf16x8 a, bf16x8 b, f32x4 c) {
  return __builtin_amdgcn_mfma_f32_16x16x32_bf16(a, b, c, 0, 0, 0);
}

// async global->LDS, 16B per lane; LDS dest must be waveBase + lane*16
__device__ __forceinline__ void gload16(const unsigned short* g, unsigned short* l) {
  __builtin_amdgcn_global_load_lds((__attribute__((address_space(1))) void*)g,
                                   (__attribute__((address_space(3))) void*)l, 16, 0, 0);
}

// ---------- batched transposing weight cast: out[n][k] = bf16(in[k][n]) ----------
__global__ __launch_bounds__(256) void tcast_all(const float* __restrict__ wq,
                                                 const float* __restrict__ wk,
                                                 const float* __restrict__ wv,
                                                 const float* __restrict__ wo,
                                                 const float* __restrict__ w1,
                                                 const float* __restrict__ w2,
                                                 unsigned short* __restrict__ wqkv_t,
                                                 unsigned short* __restrict__ wo_t,
                                                 unsigned short* __restrict__ w1_t,
                                                 unsigned short* __restrict__ w2_t) {
  const int id = blockIdx.x;
  const float* in; unsigned short* out; int K, N, k0, n0;
  if (id < 4096) {             // wq/wk/wv/wo: 1024x1024 each
    const int seg = id >> 10, r = id & 1023;
    in  = seg == 0 ? wq : seg == 1 ? wk : seg == 2 ? wv : wo;
    out = seg == 3 ? wo_t : wqkv_t + (size_t)seg * 1024 * 1024;
    K = 1024; N = 1024; n0 = (r & 31) * 32; k0 = (r >> 5) * 32;
  } else if (id < 8192) {      // w1: K=1024 -> N=4096
    const int r = id - 4096;
    in = w1; out = w1_t; K = 1024; N = 4096;
    n0 = (r & 127) * 32; k0 = (r >> 7) * 32;
  } else {                     // w2: K=4096 -> N=1024
    const int r = id - 8192;
    in = w2; out = w2_t; K = 4096; N = 1024;
    n0 = (r & 31) * 32; k0 = (r >> 5) * 32;
  }
  __shared__ float tile[32][33];
  const int tx = threadIdx.x & 31, ty = threadIdx.x >> 5;
  #pragma unroll
  for (int j = 0; j < 4; ++j)
    tile[ty + 8 * j][tx] = in[(size_t)(k0 + ty + 8 * j) * N + n0 + tx];
  __syncthreads();
  #pragma unroll
  for (int j = 0; j < 4; ++j)
    out[(size_t)(n0 + ty + 8 * j) * K + k0 + tx] = f2bf(tile[tx][ty + 8 * j]);
}

// ---------- layernorm (D=1024): FPIN=1 fp32 input, else bf16 input ----------
template <int FPIN>
__global__ __launch_bounds__(256) void ln_kernel(const void* __restrict__ xin,
                                                 const float* __restrict__ g,
                                                 const float* __restrict__ bb,
                                                 unsigned short* __restrict__ out) {
  const int row = blockIdx.x, tid = threadIdx.x;
  float4 xv;
  if (FPIN) {
    xv = ((const float4*)((const float*)xin + (size_t)row * D_MODEL))[tid];
  } else {
    const u16x4 bv4 = ((const u16x4*)((const unsigned short*)xin + (size_t)row * D_MODEL))[tid];
    xv.x = bf2f(bv4.x); xv.y = bf2f(bv4.y); xv.z = bf2f(bv4.z); xv.w = bf2f(bv4.w);
  }
  float s  = xv.x + xv.y + xv.z + xv.w;
  float ss = xv.x * xv.x + xv.y * xv.y + xv.z * xv.z + xv.w * xv.w;
  #pragma unroll
  for (int off = 1; off < 64; off <<= 1) { s += __shfl_xor(s, off); ss += __shfl_xor(ss, off); }
  __shared__ float red[8];
  const int wave = tid >> 6, lane = tid & 63;
  if (lane == 0) { red[wave] = s; red[4 + wave] = ss; }
  __syncthreads();
  s  = red[0] + red[1] + red[2] + red[3];
  ss = red[4] + red[5] + red[6] + red[7];
  const float mu   = s * (1.0f / D_MODEL);
  const float var  = ss * (1.0f / D_MODEL) - mu * mu;
  const float rstd = rsqrtf(var + 1e-5f);
  const float4 gv = ((const float4*)g)[tid];
  const float4 bv = ((const float4*)bb)[tid];
  u16x4 o;
  o.x = f2bf((xv.x - mu) * rstd * gv.x + bv.x);
  o.y = f2bf((xv.y - mu) * rstd * gv.y + bv.y);
  o.z = f2bf((xv.z - mu) * rstd * gv.z + bv.z);
  o.w = f2bf((xv.w - mu) * rstd * gv.w + bv.w);
  *(u16x4*)(out + (size_t)row * D_MODEL + tid * 4) = o;
}

// ---------- GEMM (legacy 128x128, used for WO): C = A * Bt^T ----------
template <bool BIAS, bool RELU, int RES, bool OBF>
__global__ __launch_bounds__(256) void gemm_bt(const unsigned short* __restrict__ A,
                                               const unsigned short* __restrict__ Bt,
                                               const float* __restrict__ bias,
                                               const void* __restrict__ res,
                                               void* __restrict__ out,
                                               int M, int N, int K) {
  __shared__ __align__(16) unsigned short As[128 * 64];
  __shared__ __align__(16) unsigned short Bs[128 * 64];
  const int tid  = threadIdx.x;
  const int lin = blockIdx.y * gridDim.x + blockIdx.x;   // gridDim.y == 64 always
  const int xcd = lin & 7, idx = lin >> 3;
  const int by = xcd * 8 + (idx & 7);
  const int bx = idx >> 3;
  const int row0 = by * 128, col0 = bx * 128;
  const int wave = tid >> 6, lane = tid & 63;
  const int wm = wave >> 1, wn = wave & 1;
  const int l15 = lane & 15, quad = lane >> 4;
  f32x4 acc[4][4] = {};

  const int tr = tid >> 3;                        // base row 0..31
  const int tc = (tid & 7) ^ (tr & 7);            // swizzled source chunk
  const unsigned short* gA = A  + (size_t)(row0 + tr) * K + tc * 8;
  const unsigned short* gB = Bt + (size_t)(col0 + tr) * K + tc * 8;

  const int rowA = (wm * 64 + l15) * 64;
  const int rowB = (wn * 64 + l15) * 64;
  const int swz0 = (quad ^ (l15 & 7)) * 8;
  const int swz1 = ((4 + quad) ^ (l15 & 7)) * 8;

  for (int k0 = 0; k0 < K; k0 += 64) {
    #pragma unroll
    for (int i = 0; i < 4; ++i) {
      gload16(gA + (size_t)(i * 32) * K + k0, As + (i * 256 + tid) * 8);
      gload16(gB + (size_t)(i * 32) * K + k0, Bs + (i * 256 + tid) * 8);
    }
    __syncthreads();
    #pragma unroll
    for (int kf = 0; kf < 2; ++kf) {
      const int swz = kf ? swz1 : swz0;
      bf16x8 af[4], bfr[4];
      #pragma unroll
      for (int t = 0; t < 4; ++t) {
        af[t]  = load8bf(As + rowA + t * 1024 + swz);
        bfr[t] = load8bf(Bs + rowB + t * 1024 + swz);
      }
      #pragma unroll
      for (int i = 0; i < 4; ++i)
        #pragma unroll
        for (int j = 0; j < 4; ++j)
          acc[i][j] = mfma16(af[i], bfr[j], acc[i][j]);
    }
    __syncthreads();
  }

  const size_t rbase = (size_t)row0 + wm * 64 + quad * 4;
  const int cbase = col0 + wn * 64 + l15;
  #pragma unroll
  for (int i = 0; i < 4; ++i) {
    #pragma unroll
    for (int j = 0; j < 4; ++j) {
      const int col = cbase + j * 16;
      const float bval = BIAS ? bias[col] : 0.0f;
      #pragma unroll
      for (int r = 0; r < 4; ++r) {
        const size_t row = rbase + i * 16 + r;
        float v = acc[i][j][r];
        if (BIAS) v += bval;
        if (RELU) v = fmaxf(v, 0.0f);
        if (RES == 1) v += ((const float*)res)[row * N + col];
        if (RES == 2) v += bf2f(((const unsigned short*)res)[row * N + col]);
        if (OBF)  ((unsigned short*)out)[row * N + col] = f2bf(v);
        else      ((float*)out)[row * N + col] = v;
      }
    }
  }
}

// ---------- BK=32 staging: one 128-row x 32-col half (8KB), 1 gload/thread ----------
// Paired-row lines: LDS line L (128B) holds rows 2L,2L+1; chunk p at line L holds
// global (row = 2L+(c>>2), colchunk = c&3) with c = p ^ (L&7). LDS dest stays
// linear (gload_lds constraint); the swizzle lives in the global source address.
__device__ __forceinline__ void stage32(const unsigned short* __restrict__ src,
                                        unsigned short* dst, int ld, int k0,
                                        int h, int tid) {
  const int L = tid >> 3;               // line within half (0..63)
  const int p = tid & 7;
  const int c = p ^ (L & 7);
  const int row = h * 128 + L * 2 + (c >> 2);
  gload16(src + (size_t)row * ld + k0 + (c & 3) * 8, dst + h * 4096 + tid * 8);
}

// read one 16-row x 32-col fragment: rows r0+l15, k-dims quad*8..+8
// chunk = ((row&1)*4 + quad) ^ (line&7). 256 words spread 8 per bank (even) ->
// conflict-free (verified: SQ_LDS_BANK_CONFLICT == 0 in round-6 profile).
__device__ __forceinline__ bf16x8 frag32(const unsigned short* tile, int r0,
                                         int l15, int quad) {
  const int row = r0 + l15;
  const int L = row >> 1;
  const int p = ((row & 1) * 4 + quad) ^ (L & 7);
  return load8bf(tile + L * 64 + p * 8);
}

// ---------- 256x128 GEMM, BK=32, 48KB LDS -> 2 blocks/CU (m114 overlap) ----------
// 8 waves (4Mx2N), wave tile 64x64, acc[4][4] = 64 regs -> fits the 128-reg cap
// at __launch_bounds__(512,4) WITHOUT spill (round-6 failure mode was acc[8][4]
// = 128 regs spilling to scratch: 1.86GB scratch writes, VGPR capped at 64).
// Co-resident block's waves share no barriers with ours -> its ds_read/stage
// traffic overlaps our MFMA cluster (m114: time = max(pipes), not sum).
// Per K-tile: P1 {read all B + a01 | stage A(t+1)->other buf | 8 MFMA | barrier},
// P2 {read a23 | stage B(t+2)->cur-B (fully read in P1) | 8 MFMA | vmcnt(1) |
// barrier}. vmcnt(1) drains exactly {B(t+1), A(t+1)x2}, leaves B(t+2) in flight.
template <bool BIAS, bool RELU, int RES, bool OBF, bool QKV, bool SPLITK>
__global__ __launch_bounds__(512, 4) void gemm256(const unsigned short* __restrict__ A,
                                                  const unsigned short* __restrict__ Bt,
                                                  const float* __restrict__ bias,
                                                  const void* __restrict__ res,
                                                  void* __restrict__ out,
                                                  unsigned short* __restrict__ qb,
                                                  unsigned short* __restrict__ kp,
                                                  unsigned short* __restrict__ vt,
                                                  int M, int N, int K, int lda, int ldb) {
  __shared__ __align__(16) unsigned short lds[2][12288];  // [buf][ A 8192sh | B 4096sh ]
  const int tid = threadIdx.x;
  const int lin = blockIdx.y * gridDim.x + blockIdx.x;    // gridDim.y == 32 (M = 8192)
  const int xcd = lin & 7, idx = lin >> 3;
  const int by = xcd * 4 + (idx & 3);
  const int bxr = idx >> 2;
  const int ncol = N >> 7;
  const int ks  = SPLITK ? (bxr >= ncol ? 1 : 0) : 0;
  const int bx  = SPLITK ? (bxr - ks * ncol) : bxr;
  const int row0 = by * 256, col0 = bx * 128;
  const int koff = SPLITK ? ks * K : 0;                   // K = half-depth under split
  const int wave = tid >> 6, lane = tid & 63;
  const int wm = wave >> 1, wn = wave & 1;                // 4 x 2 waves, 64x64 each
  const int l15 = lane & 15, quad = lane >> 4;

  const unsigned short* gA = A  + (size_t)row0 * lda + koff;
  const unsigned short* gB = Bt + (size_t)col0 * ldb + koff;

  unsigned short* As0 = &lds[0][0];
  unsigned short* Bs0 = &lds[0][8192];
  unsigned short* As1 = &lds[1][0];
  unsigned short* Bs1 = &lds[1][8192];

  f32x4 acc[4][4] = {};
  const int KT = K >> 5;

  // ---- prologue: tile0 A+B -> buf0; tile1 B -> buf1 (stays in flight) ----
  stage32(gA, As0, lda, 0, 0, tid);
  stage32(gA, As0, lda, 0, 1, tid);
  stage32(gB, Bs0, ldb, 0, 0, tid);
  if (KT > 1) {
    stage32(gB, Bs1, ldb, 32, 0, tid);
    asm volatile("s_waitcnt vmcnt(1)" ::: "memory");
  } else {
    asm volatile("s_waitcnt vmcnt(0)" ::: "memory");
  }
  asm volatile("s_barrier" ::: "memory");

  for (int t = 0; t < KT; ++t) {
    unsigned short* As  = (t & 1) ? As1 : As0;
    unsigned short* Bs  = (t & 1) ? Bs1 : Bs0;
    unsigned short* Asn = (t & 1) ? As0 : As1;
    const int k1 = (t + 1) << 5, k2 = (t + 2) << 5;
    bf16x8 a[2], b[4];

    // ===== P1: read ALL B + a[0..1]; stage A(t+1)->other buf; MFMA a01 x b =====
    #pragma unroll
    for (int j = 0; j < 4; ++j) b[j] = frag32(Bs, wn * 64 + j * 16, l15, quad);
    #pragma unroll
    for (int i = 0; i < 2; ++i) a[i] = frag32(As, wm * 64 + i * 16, l15, quad);
    if (t + 1 < KT) {
      stage32(gA, Asn, lda, k1, 0, tid);
      stage32(gA, Asn, lda, k1, 1, tid);
    }
    __builtin_amdgcn_s_setprio(1);
    #pragma unroll
    for (int i = 0; i < 2; ++i)
      #pragma unroll
      for (int j = 0; j < 4; ++j)
        acc[i][j] = mfma16(a[i], b[j], acc[i][j]);
    __builtin_amdgcn_s_setprio(0);
    __builtin_amdgcn_sched_barrier(0);
    asm volatile("s_barrier" ::: "memory");   // all waves' B reads of tile t done

    // ===== P2: read a[2..3]; stage B(t+2)->cur-B (consumed); MFMA a23 x b =====
    #pragma unroll
    for (int i = 0; i < 2; ++i) a[i] = frag32(As, wm * 64 + 32 + i * 16, l15, quad);
    if (t + 2 < KT) stage32(gB, Bs, ldb, k2, 0, tid);
    __builtin_amdgcn_s_setprio(1);
    #pragma unroll
    for (int i = 0; i < 2; ++i)
      #pragma unroll
      for (int j = 0; j < 4; ++j)
        acc[2 + i][j] = mfma16(a[i], b[j], acc[2 + i][j]);
    __builtin_amdgcn_s_setprio(0);
    __builtin_amdgcn_sched_barrier(0);
    if (t + 2 < KT) asm volatile("s_waitcnt vmcnt(1)" ::: "memory");
    else            asm volatile("s_waitcnt vmcnt(0)" ::: "memory");
    asm volatile("s_barrier" ::: "memory");
  }

  // ---- epilogue: wave tile 64x64 at (wm*64, wn*64) ----
  const size_t rbase = (size_t)row0 + wm * 64 + quad * 4;
  const int cbase = col0 + wn * 64 + l15;
  if (QKV) {
    const int sec = col0 >> 10;           // block-uniform (128 | 1024): 0=Q, 1=K, 2=V
    #pragma unroll
    for (int i = 0; i < 4; ++i) {
      #pragma unroll
      for (int j = 0; j < 4; ++j) {
        const int col = cbase + j * 16;
        if (sec == 0) {
          #pragma unroll
          for (int r = 0; r < 4; ++r) {
            const size_t row = rbase + i * 16 + r;
            qb[row * 1024 + col] = f2bf(acc[i][j][r] * QSCALE);
          }
        } else if (sec == 1) {
          const int c2 = col - 1024, hh = c2 >> 6, d = c2 & 63;
          #pragma unroll
          for (int r = 0; r < 4; ++r) {
            const size_t row = rbase + i * 16 + r;
            const int bb = (int)(row >> 11), tt = (int)(row & 2047);
            kp[(((size_t)(bb * 16 + hh)) * SEQ + tt) * 64 + d] = f2bf(acc[i][j][r]);
          }
        } else {
          const int c2 = col - 2048, hh = c2 >> 6, d = c2 & 63;
          const size_t t0 = rbase + i * 16;
          const int bb = (int)(t0 >> 11);
          u16x4 pk;
          #pragma unroll
          for (int r = 0; r < 4; ++r) pk[r] = f2bf(acc[i][j][r]);
          *(u16x4*)(vt + ((size_t)(bb * 16 + hh) * 64 + d) * SEQ + (t0 & 2047)) = pk;
        }
      }
    }
  } else if (SPLITK) {
    float* po = (float*)out + (size_t)ks * M * N;
    #pragma unroll
    for (int i = 0; i < 4; ++i) {
      #pragma unroll
      for (int j = 0; j < 4; ++j) {
        const int col = cbase + j * 16;
        #pragma unroll
        for (int r = 0; r < 4; ++r) {
          const size_t row = rbase + i * 16 + r;
          po[row * N + col] = acc[i][j][r];
        }
      }
    }
  } else {
    #pragma unroll
    for (int i = 0; i < 4; ++i) {
      #pragma unroll
      for (int j = 0; j < 4; ++j) {
        const int col = cbase + j * 16;
        const float bval = BIAS ? bias[col] : 0.0f;
        #pragma unroll
        for (int r = 0; r < 4; ++r) {
          const size_t row = rbase + i * 16 + r;
          float v = acc[i][j][r];
          if (BIAS) v += bval;
          if (RELU) v = fmaxf(v, 0.0f);
          if (RES == 1) v += ((const float*)res)[row * N + col];
          if (RES == 2) v += bf2f(((const unsigned short*)res)[row * N + col]);
          if (OBF)  ((unsigned short*)out)[row * N + col] = f2bf(v);
          else      ((float*)out)[row * N + col] = v;
        }
      }
    }
  }
  (void)M;
}

// ---------- split-K reduce: out = p0 + p1 + b2 + bf16(x1b), fp32 out ----------
__global__ __launch_bounds__(256) void ffn2_reduce(const float* __restrict__ p0,
                                                   const float* __restrict__ p1,
                                                   const float* __restrict__ b2,
                                                   const unsigned short* __restrict__ x1b,
                                                   float* __restrict__ out) {
  const size_t i4 = (size_t)blockIdx.x * 256 + threadIdx.x;   // float4 index
  const float4 a = ((const float4*)p0)[i4];
  const float4 b = ((const float4*)p1)[i4];
  const float4 bi = ((const float4*)b2)[i4 & 255];            // 1024/4 = 256 groups/row
  const u16x4 rv = ((const u16x4*)x1b)[i4];
  float4 o;
  o.x = a.x + b.x + bi.x + bf2f(rv.x);
  o.y = a.y + b.y + bi.y + bf2f(rv.y);
  o.z = a.z + b.z + bi.z + bf2f(rv.z);
  o.w = a.w + b.w + bi.w + bf2f(rv.w);
  ((float4*)out)[i4] = o;
}

// ---------- fused causal attention v5 ----------
__global__ __launch_bounds__(256) void attn5(const unsigned short* __restrict__ qb,
                                             const unsigned short* __restrict__ kp,
                                             const unsigned short* __restrict__ vt,
                                             unsigned short* __restrict__ attnb) {
  const int lin = (blockIdx.z * 16 + blockIdx.y) * 8 + blockIdx.x;  // 512 blocks
  const int xcd = lin & 7, idx = lin >> 3;
  const int bh = xcd * 8 + (idx >> 3);
  const int xb = idx & 7;
  const int b = bh >> 4, h = bh & 15;
  const int tid = threadIdx.x, wave = tid >> 6, lane = tid & 63;
  const int l15 = lane & 15, quad = lane >> 4;
  const size_t tokbase = (size_t)b * SEQ;

  __shared__ __align__(16) unsigned short ks[64 * 64];       // [key][dim], chunk-swizzled
  __shared__ __align__(16) unsigned short vts[64 * 64];      // [dim][key], chunk-swizzled
  __shared__ __align__(16) unsigned short plds[4][32 * 64];  // per-wave P[q][key], swizzled

  const unsigned short* kbase = kp + (size_t)bh * SEQ * HDIM;
  const unsigned short* vbase = vt + (size_t)bh * HDIM * SEQ;

  for (int half = 0; half < 2; ++half) {
    const int qblk = (half == 0) ? (15 - xb) : xb;
    const int qw0 = qblk * 128 + wave * 32;

    bf16x8 qf[2][2];   // [qf][kf]: rows qw0+qf*16+l15, dims kf*32+quad*8..+8
    #pragma unroll
    for (int qfi = 0; qfi < 2; ++qfi)
      #pragma unroll
      for (int kf = 0; kf < 2; ++kf)
        qf[qfi][kf] = load8bf(qb + (tokbase + qw0 + qfi * 16 + l15) * 1024
                              + h * HDIM + kf * 32 + quad * 8);

    f32x4 o[2][4] = {};
    float lsum[2] = {0.0f, 0.0f};

    const int ntiles = qblk * 2 + 2;
    for (int kt = 0; kt < ntiles; ++kt) {
      const int k0 = kt * 64;
      __syncthreads();                       // previous tile fully consumed
      #pragma unroll
      for (int i = 0; i < 2; ++i) {          // stage K tile (8KB)
        const int cid = i * 256 + tid;
        const int r = cid >> 3, p = cid & 7, c = p ^ (r & 7);
        gload16(kbase + (size_t)(k0 + r) * HDIM + c * 8, ks + cid * 8);
      }
      #pragma unroll
      for (int i = 0; i < 2; ++i) {          // stage V^T tile (8KB)
        const int cid = i * 256 + tid;
        const int d = cid >> 3, p = cid & 7, c = p ^ (d & 7);
        gload16(vbase + (size_t)d * SEQ + k0 + c * 8, vts + cid * 8);
      }
      __syncthreads();                       // vmcnt drain -> staged data visible
      if (k0 <= qw0 + 31) {
        // ---- QK^T (swapped): s[keyf][qfi] ----
        f32x4 s[4][2] = {};
        #pragma unroll
        for (int kf = 0; kf < 2; ++kf)
          #pragma unroll
          for (int keyf = 0; keyf < 4; ++keyf) {
            const int row = keyf * 16 + l15;
            const int p = (kf * 4 + quad) ^ (row & 7);
            const bf16x8 kfr = load8bf(ks + row * 64 + p * 8);
            s[keyf][0] = mfma16(kfr, qf[0][kf], s[keyf][0]);
            s[keyf][1] = mfma16(kfr, qf[1][kf], s[keyf][1]);
          }
        // ---- fixed-max softmax + packed P store ----
        #pragma unroll
        for (int qfi = 0; qfi < 2; ++qfi) {
          const int q = qw0 + qfi * 16 + l15;
          const int qloc = qfi * 16 + l15;
          #pragma unroll
          for (int keyf = 0; keyf < 4; ++keyf) {
            unsigned int pw[4];
            #pragma unroll
            for (int r = 0; r < 4; ++r) {
              const int key = k0 + keyf * 16 + quad * 4 + r;
              float p = __builtin_amdgcn_exp2f(s[keyf][qfi][r]);
              p = (key > q) ? 0.0f : p;
              pw[r] = __builtin_bit_cast(unsigned int, p);
              lsum[qfi] += __builtin_bit_cast(float, pw[r] & 0xFFFF0000u);
            }
            u32x2 packed;
            packed.x = (pw[0] >> 16) | (pw[1] & 0xFFFF0000u);
            packed.y = (pw[2] >> 16) | (pw[3] & 0xFFFF0000u);
            const int slot = (keyf * 4 + quad) ^ ((l15 & 7) << 1);
            *(u32x2*)(&plds[wave][qloc * 64 + slot * 4]) = packed;
          }
        }
        __builtin_amdgcn_s_waitcnt(0);       // wave-local plds writes -> reads
        // ---- PV: A=P (m=q,k=key), B=V^T (n=d,k=key) ----
        #pragma unroll
        for (int kf = 0; kf < 2; ++kf) {
          bf16x8 pa[2];
          #pragma unroll
          for (int mf = 0; mf < 2; ++mf) {
            const int lq = mf * 16 + l15;
            const int c = (kf * 4 + quad) ^ (l15 & 7);
            pa[mf] = load8bf(&plds[wave][lq * 64 + c * 8]);
          }
          #pragma unroll
          for (int df = 0; df < 4; ++df) {
            const int row = df * 16 + l15;
            const int p = (kf * 4 + quad) ^ (row & 7);
            const bf16x8 vb = load8bf(vts + row * 64 + p * 8);
            o[0][df] = mfma16(pa[0], vb, o[0][df]);
            o[1][df] = mfma16(pa[1], vb, o[1][df]);
          }
        }
      }
    }
    // ---- normalize + write ----
    #pragma unroll
    for (int mf = 0; mf < 2; ++mf) {
      float l = lsum[mf];
      l += __shfl_xor(l, 16);
      l += __shfl_xor(l, 32);
      const float rl = 1.0f / l;
      #pragma unroll
      for (int r = 0; r < 4; ++r) {
        const float rv = __shfl(rl, quad * 4 + r);   // lane holding q=..+quad*4+r
        const size_t row = tokbase + qw0 + mf * 16 + quad * 4 + r;
        #pragma unroll
        for (int df = 0; df < 4; ++df)
          attnb[row * D_MODEL + h * HDIM + df * 16 + l15] = f2bf(o[mf][df][r] * rv);
      }
    }
  }
}

// ---------- host ----------
extern "C" void kernel_launch(void* const* d_in, const int* in_sizes, int n_in,
                              void* d_out, int out_size, void* d_ws, size_t ws_size,
                              hipStream_t stream) {
  const float* x    = (const float*)d_in[0];
  const float* wq   = (const float*)d_in[1];
  const float* wk   = (const float*)d_in[2];
  const float* wv   = (const float*)d_in[3];
  const float* wo   = (const float*)d_in[4];
  const float* bo   = (const float*)d_in[5];
  const float* w1   = (const float*)d_in[6];
  const float* b1   = (const float*)d_in[7];
  const float* w2   = (const float*)d_in[8];
  const float* b2   = (const float*)d_in[9];
  const float* g1   = (const float*)d_in[10];
  const float* bl1  = (const float*)d_in[11];
  const float* g2   = (const float*)d_in[12];
  const float* bl2  = (const float*)d_in[13];
  float* out = (float*)d_out;

  char* ws = (char*)d_ws;
  size_t off = 0;
  auto alloc = [&](size_t bytes) { char* p = ws + off; off += (bytes + 255) & ~(size_t)255; return p; };
  unsigned short* wqkv_t = (unsigned short*)alloc((size_t)3072 * 1024 * 2);
  unsigned short* wo_t   = (unsigned short*)alloc((size_t)1024 * 1024 * 2);
  unsigned short* w1_t   = (unsigned short*)alloc((size_t)4096 * 1024 * 2);
  unsigned short* w2_t   = (unsigned short*)alloc((size_t)1024 * 4096 * 2);
  unsigned short* h1     = (unsigned short*)alloc((size_t)NTOK * 1024 * 2);
  unsigned short* kpb    = (unsigned short*)alloc((size_t)NTOK * 1024 * 2);  // K packed
  unsigned short* vtb    = (unsigned short*)alloc((size_t)NTOK * 1024 * 2);  // V^T packed
  unsigned short* attnb  = (unsigned short*)alloc((size_t)NTOK * 1024 * 2);
  unsigned short* h2     = (unsigned short*)alloc((size_t)NTOK * 1024 * 2);
  unsigned short* ffn1   = (unsigned short*)alloc((size_t)NTOK * 4096 * 2);
  // qb aliases attnb; x1b aliases h1 (dead after QKV GEMM).
  unsigned short* qb  = attnb;
  unsigned short* x1b = h1;
  // FFN2 split-K fp32 partials (2 x 32MB) alias kpb..h2 (all dead after FFN1):
  // kpb,vtb,attnb,h2 are 4 contiguous 16MB regions = exactly 64MB.
  float* part = (float*)kpb;

  tcast_all<<<12288, 256, 0, stream>>>(wq, wk, wv, wo, w1, w2,
                                       wqkv_t, wo_t, w1_t, w2_t);
  ln_kernel<1><<<NTOK, 256, 0, stream>>>(x, g1, bl1, h1);
  // fused QKV: 24x32 = 768 blocks (1.5 rounds of 512-slot capacity)
  gemm256<false, false, 0, true, true, false><<<dim3(24, 32), 512, 0, stream>>>(
      h1, wqkv_t, nullptr, nullptr, nullptr, qb, kpb, vtb, NTOK, 3072, 1024, 1024, 1024);
  attn5<<<dim3(SEQ / 256, NHEAD, NBATCH), 256, 0, stream>>>(qb, kpb, vtb, attnb);
  // x1 = x + attn @ wo + bo  -> bf16 x1b   (legacy 128^2)
  gemm_bt<true, false, 1, true><<<dim3(8, 64), 256, 0, stream>>>(
      attnb, wo_t, bo, x, x1b, NTOK, 1024, 1024);
  ln_kernel<0><<<NTOK, 256, 0, stream>>>(x1b, g2, bl2, h2);
  // FFN1: 32x32 = 1024 blocks = 2 exact rounds at 2 blocks/CU
  gemm256<true, true, 0, true, false, false><<<dim3(32, 32), 512, 0, stream>>>(
      h2, w1_t, b1, nullptr, ffn1, nullptr, nullptr, nullptr, NTOK, 4096, 1024, 1024, 1024);
  // FFN2 (split-K=2): 16x32 = 512 blocks = 1 exact round
  gemm256<false, false, 0, false, false, true><<<dim3(16, 32), 512, 0, stream>>>(
      ffn1, w2_t, nullptr, nullptr, part, nullptr, nullptr, nullptr,
      NTOK, 1024, 2048, 4096, 4096);
  // out = part0 + part1 + b2 + x1b (fp32 out)
  ffn2_reduce<<<NTOK * 1024 / 4 / 256, 256, 0, stream>>>(
      part, part + (size_t)NTOK * 1024, b2, x1b, out);
  (void)in_sizes; (void)n_in; (void)out_size; (void)ws_size;
}

// Round 8
// 447.270 us; speedup vs baseline: 4.0161x; 1.0557x over previous
//
#include <hip/hip_runtime.h>
#include <cstdint>

// ---------- types ----------
typedef __bf16 bf16x8 __attribute__((ext_vector_type(8)));
typedef float f32x4 __attribute__((ext_vector_type(4)));
typedef unsigned int u32x4 __attribute__((ext_vector_type(4)));
typedef unsigned int u32x2 __attribute__((ext_vector_type(2)));
typedef unsigned short u16x4 __attribute__((ext_vector_type(4)));

#define D_MODEL 1024
#define SEQ     2048
#define NBATCH  4
#define NHEAD   16
#define HDIM    64
#define NTOK    (NBATCH * SEQ)   // 8192
#define QSCALE  0.18033688011112042f   // 0.125 * log2(e)

__device__ __forceinline__ unsigned short f2bf(float f) {
  unsigned int u = __builtin_bit_cast(unsigned int, f);
  u += 0x7FFFu + ((u >> 16) & 1u);           // round-to-nearest-even
  return (unsigned short)(u >> 16);
}

__device__ __forceinline__ float bf2f(unsigned short s) {
  return __builtin_bit_cast(float, (unsigned int)s << 16);
}

__device__ __forceinline__ bf16x8 load8bf(const unsigned short* p) {
  return __builtin_bit_cast(bf16x8, *(const u32x4*)p);
}

__device__ __forceinline__ f32x4 mfma16(bf16x8 a, bf16x8 b, f32x4 c) {
  return __builtin_amdgcn_mfma_f32_16x16x32_bf16(a, b, c, 0, 0, 0);
}

// async global->LDS, 16B per lane; LDS dest must be waveBase + lane*16
__device__ __forceinline__ void gload16(const unsigned short* g, unsigned short* l) {
  __builtin_amdgcn_global_load_lds((__attribute__((address_space(1))) void*)g,
                                   (__attribute__((address_space(3))) void*)l, 16, 0, 0);
}

// ---------- batched transposing weight cast: out[n][k] = bf16(in[k][n]) ----------
__global__ __launch_bounds__(256) void tcast_all(const float* __restrict__ wq,
                                                 const float* __restrict__ wk,
                                                 const float* __restrict__ wv,
                                                 const float* __restrict__ wo,
                                                 const float* __restrict__ w1,
                                                 const float* __restrict__ w2,
                                                 unsigned short* __restrict__ wqkv_t,
                                                 unsigned short* __restrict__ wo_t,
                                                 unsigned short* __restrict__ w1_t,
                                                 unsigned short* __restrict__ w2_t) {
  const int id = blockIdx.x;
  const float* in; unsigned short* out; int K, N, k0, n0;
  if (id < 4096) {             // wq/wk/wv/wo: 1024x1024 each
    const int seg = id >> 10, r = id & 1023;
    in  = seg == 0 ? wq : seg == 1 ? wk : seg == 2 ? wv : wo;
    out = seg == 3 ? wo_t : wqkv_t + (size_t)seg * 1024 * 1024;
    K = 1024; N = 1024; n0 = (r & 31) * 32; k0 = (r >> 5) * 32;
  } else if (id < 8192) {      // w1: K=1024 -> N=4096
    const int r = id - 4096;
    in = w1; out = w1_t; K = 1024; N = 4096;
    n0 = (r & 127) * 32; k0 = (r >> 7) * 32;
  } else {                     // w2: K=4096 -> N=1024
    const int r = id - 8192;
    in = w2; out = w2_t; K = 4096; N = 1024;
    n0 = (r & 31) * 32; k0 = (r >> 5) * 32;
  }
  __shared__ float tile[32][33];
  const int tx = threadIdx.x & 31, ty = threadIdx.x >> 5;
  #pragma unroll
  for (int j = 0; j < 4; ++j)
    tile[ty + 8 * j][tx] = in[(size_t)(k0 + ty + 8 * j) * N + n0 + tx];
  __syncthreads();
  #pragma unroll
  for (int j = 0; j < 4; ++j)
    out[(size_t)(n0 + ty + 8 * j) * K + k0 + tx] = f2bf(tile[tx][ty + 8 * j]);
}

// ---------- layernorm (D=1024): FPIN=1 fp32 input, else bf16 input ----------
template <int FPIN>
__global__ __launch_bounds__(256) void ln_kernel(const void* __restrict__ xin,
                                                 const float* __restrict__ g,
                                                 const float* __restrict__ bb,
                                                 unsigned short* __restrict__ out) {
  const int row = blockIdx.x, tid = threadIdx.x;
  float4 xv;
  if (FPIN) {
    xv = ((const float4*)((const float*)xin + (size_t)row * D_MODEL))[tid];
  } else {
    const u16x4 bv4 = ((const u16x4*)((const unsigned short*)xin + (size_t)row * D_MODEL))[tid];
    xv.x = bf2f(bv4.x); xv.y = bf2f(bv4.y); xv.z = bf2f(bv4.z); xv.w = bf2f(bv4.w);
  }
  float s  = xv.x + xv.y + xv.z + xv.w;
  float ss = xv.x * xv.x + xv.y * xv.y + xv.z * xv.z + xv.w * xv.w;
  #pragma unroll
  for (int off = 1; off < 64; off <<= 1) { s += __shfl_xor(s, off); ss += __shfl_xor(ss, off); }
  __shared__ float red[8];
  const int wave = tid >> 6, lane = tid & 63;
  if (lane == 0) { red[wave] = s; red[4 + wave] = ss; }
  __syncthreads();
  s  = red[0] + red[1] + red[2] + red[3];
  ss = red[4] + red[5] + red[6] + red[7];
  const float mu   = s * (1.0f / D_MODEL);
  const float var  = ss * (1.0f / D_MODEL) - mu * mu;
  const float rstd = rsqrtf(var + 1e-5f);
  const float4 gv = ((const float4*)g)[tid];
  const float4 bv = ((const float4*)bb)[tid];
  u16x4 o;
  o.x = f2bf((xv.x - mu) * rstd * gv.x + bv.x);
  o.y = f2bf((xv.y - mu) * rstd * gv.y + bv.y);
  o.z = f2bf((xv.z - mu) * rstd * gv.z + bv.z);
  o.w = f2bf((xv.w - mu) * rstd * gv.w + bv.w);
  *(u16x4*)(out + (size_t)row * D_MODEL + tid * 4) = o;
}

// ---------- GEMM (legacy 128x128, used for WO): C = A * Bt^T ----------
template <bool BIAS, bool RELU, int RES, bool OBF>
__global__ __launch_bounds__(256) void gemm_bt(const unsigned short* __restrict__ A,
                                               const unsigned short* __restrict__ Bt,
                                               const float* __restrict__ bias,
                                               const void* __restrict__ res,
                                               void* __restrict__ out,
                                               int M, int N, int K) {
  __shared__ __align__(16) unsigned short As[128 * 64];
  __shared__ __align__(16) unsigned short Bs[128 * 64];
  const int tid  = threadIdx.x;
  const int lin = blockIdx.y * gridDim.x + blockIdx.x;   // gridDim.y == 64 always
  const int xcd = lin & 7, idx = lin >> 3;
  const int by = xcd * 8 + (idx & 7);
  const int bx = idx >> 3;
  const int row0 = by * 128, col0 = bx * 128;
  const int wave = tid >> 6, lane = tid & 63;
  const int wm = wave >> 1, wn = wave & 1;
  const int l15 = lane & 15, quad = lane >> 4;
  f32x4 acc[4][4] = {};

  const int tr = tid >> 3;                        // base row 0..31
  const int tc = (tid & 7) ^ (tr & 7);            // swizzled source chunk
  const unsigned short* gA = A  + (size_t)(row0 + tr) * K + tc * 8;
  const unsigned short* gB = Bt + (size_t)(col0 + tr) * K + tc * 8;

  const int rowA = (wm * 64 + l15) * 64;
  const int rowB = (wn * 64 + l15) * 64;
  const int swz0 = (quad ^ (l15 & 7)) * 8;
  const int swz1 = ((4 + quad) ^ (l15 & 7)) * 8;

  for (int k0 = 0; k0 < K; k0 += 64) {
    #pragma unroll
    for (int i = 0; i < 4; ++i) {
      gload16(gA + (size_t)(i * 32) * K + k0, As + (i * 256 + tid) * 8);
      gload16(gB + (size_t)(i * 32) * K + k0, Bs + (i * 256 + tid) * 8);
    }
    __syncthreads();
    #pragma unroll
    for (int kf = 0; kf < 2; ++kf) {
      const int swz = kf ? swz1 : swz0;
      bf16x8 af[4], bfr[4];
      #pragma unroll
      for (int t = 0; t < 4; ++t) {
        af[t]  = load8bf(As + rowA + t * 1024 + swz);
        bfr[t] = load8bf(Bs + rowB + t * 1024 + swz);
      }
      #pragma unroll
      for (int i = 0; i < 4; ++i)
        #pragma unroll
        for (int j = 0; j < 4; ++j)
          acc[i][j] = mfma16(af[i], bfr[j], acc[i][j]);
    }
    __syncthreads();
  }

  const size_t rbase = (size_t)row0 + wm * 64 + quad * 4;
  const int cbase = col0 + wn * 64 + l15;
  #pragma unroll
  for (int i = 0; i < 4; ++i) {
    #pragma unroll
    for (int j = 0; j < 4; ++j) {
      const int col = cbase + j * 16;
      const float bval = BIAS ? bias[col] : 0.0f;
      #pragma unroll
      for (int r = 0; r < 4; ++r) {
        const size_t row = rbase + i * 16 + r;
        float v = acc[i][j][r];
        if (BIAS) v += bval;
        if (RELU) v = fmaxf(v, 0.0f);
        if (RES == 1) v += ((const float*)res)[row * N + col];
        if (RES == 2) v += bf2f(((const unsigned short*)res)[row * N + col]);
        if (OBF)  ((unsigned short*)out)[row * N + col] = f2bf(v);
        else      ((float*)out)[row * N + col] = v;
      }
    }
  }
}

// ---------- staging helper: one 128-row x 64-col half-tile, 512 threads ----------
__device__ __forceinline__ void stage_half_512(const unsigned short* __restrict__ src,
                                               unsigned short* dst, int ld, int k0,
                                               int h, int tid) {
  #pragma unroll
  for (int l = 0; l < 2; ++l) {
    const int cid = l * 512 + tid;
    const int r = cid >> 3, p = cid & 7, c = p ^ (r & 7);
    gload16(src + (size_t)(h * 128 + r) * ld + k0 + c * 8, dst + h * 8192 + cid * 8);
  }
}

// ---------- 256x256 free-flow GEMM, BK=64 (round-5 best: QKV 76us) ----------
// 2 barriers per K-tile; mid barrier after Q-half-1 guarantees all waves' B
// ds_reads done (via each wave's MFMA lgkm wait + sched_barrier pin) before
// B(t+2) staging overwrites that region. End barrier after counted vmcnt(4).
template <bool BIAS, bool RELU, int RES, bool OBF, bool QKV>
__global__ __launch_bounds__(512, 2) void gemm256(const unsigned short* __restrict__ A,
                                                  const unsigned short* __restrict__ Bt,
                                                  const float* __restrict__ bias,
                                                  const void* __restrict__ res,
                                                  void* __restrict__ out,
                                                  unsigned short* __restrict__ qb,
                                                  unsigned short* __restrict__ kp,
                                                  unsigned short* __restrict__ vt,
                                                  int M, int N, int K) {
  __shared__ __align__(16) unsigned short lds[2][32768];  // [buf][ A 16384sh | B 16384sh ]
  const int tid = threadIdx.x;
  const int lin = blockIdx.y * gridDim.x + blockIdx.x;    // gridDim.y == 32 (M = 8192)
  const int xcd = lin & 7, idx = lin >> 3;
  const int by = xcd * 4 + (idx & 3);
  const int bx = idx >> 2;
  const int row0 = by * 256, col0 = bx * 256;
  const int wave = tid >> 6, lane = tid & 63;
  const int wm = wave >> 2, wn = wave & 3;                // 2 x 4 waves, 128x64 each
  const int l15 = lane & 15, quad = lane >> 4;
  const int swz0 = (quad ^ (l15 & 7)) * 8;
  const int swz1 = ((4 + quad) ^ (l15 & 7)) * 8;

  const unsigned short* gA = A  + (size_t)row0 * K;
  const unsigned short* gB = Bt + (size_t)col0 * K;

  unsigned short* As0 = &lds[0][0];
  unsigned short* Bs0 = &lds[0][16384];
  unsigned short* As1 = &lds[1][0];
  unsigned short* Bs1 = &lds[1][16384];

  f32x4 acc[8][4] = {};
  const int KT = K >> 6;

  // ---- prologue: tile0 (A+B) -> buf0; tile1 B halves -> buf1 ----
  stage_half_512(gA, As0, K, 0, 0, tid);
  stage_half_512(gA, As0, K, 0, 1, tid);
  stage_half_512(gB, Bs0, K, 0, 0, tid);
  stage_half_512(gB, Bs0, K, 0, 1, tid);
  if (KT > 1) {
    stage_half_512(gB, Bs1, K, 64, 0, tid);
    stage_half_512(gB, Bs1, K, 64, 1, tid);
    asm volatile("s_waitcnt vmcnt(4)" ::: "memory");
  } else {
    asm volatile("s_waitcnt vmcnt(0)" ::: "memory");
  }
  asm volatile("s_barrier" ::: "memory");

  for (int t = 0; t < KT; ++t) {
    unsigned short* As  = (t & 1) ? As1 : As0;
    unsigned short* Bs  = (t & 1) ? Bs1 : Bs0;
    unsigned short* Asn = (t & 1) ? As0 : As1;
    const int k1 = (t + 1) << 6, k2 = (t + 2) << 6;
    bf16x8 a0[2][4], b01[2][2], b23[2][2];

    // ===== half 1: read A-group0 (8) + all B (8); stage t+1.A; Q00 + Q01 =====
    #pragma unroll
    for (int i = 0; i < 4; ++i) {
      const unsigned short* ap = As + (wm * 128 + i * 16 + l15) * 64;
      a0[0][i] = load8bf(ap + swz0);
      a0[1][i] = load8bf(ap + swz1);
    }
    #pragma unroll
    for (int j = 0; j < 2; ++j) {
      const unsigned short* bp = Bs + (wn * 64 + j * 16 + l15) * 64;
      b01[0][j] = load8bf(bp + swz0);
      b01[1][j] = load8bf(bp + swz1);
      const unsigned short* bp2 = Bs + (wn * 64 + 32 + j * 16 + l15) * 64;
      b23[0][j] = load8bf(bp2 + swz0);
      b23[1][j] = load8bf(bp2 + swz1);
    }
    if (t + 1 < KT) {
      stage_half_512(gA, Asn, K, k1, 0, tid);
      stage_half_512(gA, Asn, K, k1, 1, tid);
    }
    __builtin_amdgcn_s_setprio(1);
    #pragma unroll
    for (int kf = 0; kf < 2; ++kf)
      #pragma unroll
      for (int i = 0; i < 4; ++i)
        #pragma unroll
        for (int j = 0; j < 2; ++j)
          acc[i][j] = mfma16(a0[kf][i], b01[kf][j], acc[i][j]);
    #pragma unroll
    for (int kf = 0; kf < 2; ++kf)
      #pragma unroll
      for (int i = 0; i < 4; ++i)
        #pragma unroll
        for (int j = 0; j < 2; ++j)
          acc[i][2 + j] = mfma16(a0[kf][i], b23[kf][j], acc[i][2 + j]);
    __builtin_amdgcn_s_setprio(0);
    __builtin_amdgcn_sched_barrier(0);
    asm volatile("s_barrier" ::: "memory");   // all B reads of tile t complete

    // ===== half 2: read A-group1 (reuse regs); stage t+2.B (cur buf); Q11 + Q10 =====
    #pragma unroll
    for (int i = 0; i < 4; ++i) {
      const unsigned short* ap = As + (wm * 128 + 64 + i * 16 + l15) * 64;
      a0[0][i] = load8bf(ap + swz0);
      a0[1][i] = load8bf(ap + swz1);
    }
    if (t + 2 < KT) {
      stage_half_512(gB, Bs, K, k2, 0, tid);
      stage_half_512(gB, Bs, K, k2, 1, tid);
    }
    __builtin_amdgcn_s_setprio(1);
    #pragma unroll
    for (int kf = 0; kf < 2; ++kf)
      #pragma unroll
      for (int i = 0; i < 4; ++i)
        #pragma unroll
        for (int j = 0; j < 2; ++j)
          acc[4 + i][2 + j] = mfma16(a0[kf][i], b23[kf][j], acc[4 + i][2 + j]);
    #pragma unroll
    for (int kf = 0; kf < 2; ++kf)
      #pragma unroll
      for (int i = 0; i < 4; ++i)
        #pragma unroll
        for (int j = 0; j < 2; ++j)
          acc[4 + i][j] = mfma16(a0[kf][i], b01[kf][j], acc[4 + i][j]);
    __builtin_amdgcn_s_setprio(0);
    __builtin_amdgcn_sched_barrier(0);
    if (t + 2 < KT) asm volatile("s_waitcnt vmcnt(4)" ::: "memory");
    else            asm volatile("s_waitcnt vmcnt(0)" ::: "memory");
    asm volatile("s_barrier" ::: "memory");
  }

  // ---- epilogue ----
  const size_t rbase = (size_t)row0 + wm * 128 + quad * 4;
  const int cbase = col0 + wn * 64 + l15;
  if (QKV) {
    const int sec = col0 >> 10;           // block-uniform (256 | 1024): 0=Q, 1=K, 2=V
    #pragma unroll
    for (int i = 0; i < 8; ++i) {
      #pragma unroll
      for (int j = 0; j < 4; ++j) {
        const int col = cbase + j * 16;
        if (sec == 0) {
          #pragma unroll
          for (int r = 0; r < 4; ++r) {
            const size_t row = rbase + i * 16 + r;
            qb[row * 1024 + col] = f2bf(acc[i][j][r] * QSCALE);
          }
        } else if (sec == 1) {
          const int c2 = col - 1024, hh = c2 >> 6, d = c2 & 63;
          #pragma unroll
          for (int r = 0; r < 4; ++r) {
            const size_t row = rbase + i * 16 + r;
            const int bb = (int)(row >> 11), tt = (int)(row & 2047);
            kp[(((size_t)(bb * 16 + hh)) * SEQ + tt) * 64 + d] = f2bf(acc[i][j][r]);
          }
        } else {
          const int c2 = col - 2048, hh = c2 >> 6, d = c2 & 63;
          const size_t t0 = rbase + i * 16;
          const int bb = (int)(t0 >> 11);
          u16x4 pk;
          #pragma unroll
          for (int r = 0; r < 4; ++r) pk[r] = f2bf(acc[i][j][r]);
          *(u16x4*)(vt + ((size_t)(bb * 16 + hh) * 64 + d) * SEQ + (t0 & 2047)) = pk;
        }
      }
    }
  } else {
    #pragma unroll
    for (int i = 0; i < 8; ++i) {
      #pragma unroll
      for (int j = 0; j < 4; ++j) {
        const int col = cbase + j * 16;
        const float bval = BIAS ? bias[col] : 0.0f;
        #pragma unroll
        for (int r = 0; r < 4; ++r) {
          const size_t row = rbase + i * 16 + r;
          float v = acc[i][j][r];
          if (BIAS) v += bval;
          if (RELU) v = fmaxf(v, 0.0f);
          if (RES == 1) v += ((const float*)res)[row * N + col];
          if (RES == 2) v += bf2f(((const unsigned short*)res)[row * N + col]);
          if (OBF)  ((unsigned short*)out)[row * N + col] = f2bf(v);
          else      ((float*)out)[row * N + col] = v;
        }
      }
    }
  }
  (void)M;
}

// ---------- BK=32 staging for FFN2 groups: 128 rows x 32 cols (8KB), 256 thr ----------
// Paired-row lines (round-7 verified conflict-free): line L holds rows 2L,2L+1;
// chunk p at line L holds global (row = 2L+(c>>2), colchunk = c&3), c = p^(L&7).
__device__ __forceinline__ void stage32g(const unsigned short* __restrict__ src,
                                         unsigned short* dst, int ld, int k0,
                                         int h128, int t256) {
  #pragma unroll
  for (int l = 0; l < 2; ++l) {
    const int cid = l * 256 + t256;     // 0..511
    const int L = cid >> 3;             // line 0..63
    const int p = cid & 7;
    const int c = p ^ (L & 7);
    const int row = h128 * 128 + L * 2 + (c >> 2);
    gload16(src + (size_t)row * ld + k0 + (c & 3) * 8, dst + h128 * 4096 + cid * 8);
  }
}

__device__ __forceinline__ bf16x8 frag32(const unsigned short* tile, int r0,
                                         int l15, int quad) {
  const int row = r0 + l15;
  const int L = row >> 1;
  const int p = ((row & 1) * 4 + quad) ^ (L & 7);
  return load8bf(tile + L * 64 + p * 8);
}

// ---------- FFN2: 256x128 tile, IN-BLOCK split-K=2, fused reduce+bias+residual ----------
// 8 waves = 2 K-groups (ks=wave>>2) x (2M x 2N, wave tile 128x64). Each group
// streams its K-half (2048) at BK=32 from group-private LDS (2 x 48KB = 96KB).
// Free-flow 2-barrier loop per K-tile (groups are symmetric -> shared barriers
// stay aligned). Epilogue: group1 pushes acc through LDS (2 x 64KB rounds),
// group0 adds + writes out = acc + b2 + bf16(x1b), fp32. Kills the 19us
// ffn2_reduce pass and 64MB of fp32 partial HBM writes.
__global__ __launch_bounds__(512, 2) void gemm_ffn2(const unsigned short* __restrict__ A,
                                                    const unsigned short* __restrict__ Bt,
                                                    const float* __restrict__ bias,
                                                    const unsigned short* __restrict__ res,
                                                    float* __restrict__ out) {
  __shared__ __align__(16) unsigned short lds[2][2][12288]; // [grp][buf][A 8192 | B 4096]
  const int tid = threadIdx.x;
  const int lin = blockIdx.y * gridDim.x + blockIdx.x;      // 8 x 32 = 256 blocks
  const int xcd = lin & 7, idx = lin >> 3;
  const int by = xcd * 4 + (idx & 3);
  const int bx = idx >> 2;
  const int row0 = by * 256, col0 = bx * 128;
  const int wave = tid >> 6, lane = tid & 63;
  const int ks = wave >> 2;                                 // K-group 0/1
  const int w4 = wave & 3;
  const int wm = w4 >> 1, wn = w4 & 1;                      // 2x2, wave tile 128x64
  const int l15 = lane & 15, quad = lane >> 4;
  const int t256 = tid & 255;                               // group-local thread

  const unsigned short* gA = A  + (size_t)row0 * 4096 + ks * 2048;
  const unsigned short* gB = Bt + (size_t)col0 * 4096 + ks * 2048;

  unsigned short* As0 = &lds[ks][0][0];
  unsigned short* Bs0 = &lds[ks][0][8192];
  unsigned short* As1 = &lds[ks][1][0];
  unsigned short* Bs1 = &lds[ks][1][8192];

  f32x4 acc[8][4] = {};
  const int KT = 64;                                        // 2048 / 32

  // ---- prologue: tile0 A(2 halves)+B -> buf0; tile1 B -> buf1 ----
  stage32g(gA, As0, 4096, 0, 0, t256);
  stage32g(gA, As0, 4096, 0, 1, t256);
  stage32g(gB, Bs0, 4096, 0, 0, t256);
  stage32g(gB, Bs1, 4096, 32, 0, t256);
  asm volatile("s_waitcnt vmcnt(2)" ::: "memory");          // tile0 done, tile1.B in flight
  asm volatile("s_barrier" ::: "memory");

  for (int t = 0; t < KT; ++t) {
    unsigned short* As  = (t & 1) ? As1 : As0;
    unsigned short* Bs  = (t & 1) ? Bs1 : Bs0;
    unsigned short* Asn = (t & 1) ? As0 : As1;
    const int k1 = (t + 1) << 5, k2 = (t + 2) << 5;
    bf16x8 a[4], b[4];

    // ===== P1: read all B (4) + a[0..3] (rows wm*128..+64); stage A(t+1); MFMA top =====
    #pragma unroll
    for (int j = 0; j < 4; ++j) b[j] = frag32(Bs, wn * 64 + j * 16, l15, quad);
    #pragma unroll
    for (int i = 0; i < 4; ++i) a[i] = frag32(As, wm * 128 + i * 16, l15, quad);
    if (t + 1 < KT) {
      stage32g(gA, Asn, 4096, k1, 0, t256);
      stage32g(gA, Asn, 4096, k1, 1, t256);
    }
    __builtin_amdgcn_s_setprio(1);
    #pragma unroll
    for (int i = 0; i < 4; ++i)
      #pragma unroll
      for (int j = 0; j < 4; ++j)
        acc[i][j] = mfma16(a[i], b[j], acc[i][j]);
    __builtin_amdgcn_s_setprio(0);
    __builtin_amdgcn_sched_barrier(0);
    asm volatile("s_barrier" ::: "memory");   // all B reads of tile t complete

    // ===== P2: read a[4..7]; stage B(t+2) -> cur-B (consumed in P1); MFMA bottom =====
    #pragma unroll
    for (int i = 0; i < 4; ++i) a[i] = frag32(As, wm * 128 + 64 + i * 16, l15, quad);
    if (t + 2 < KT) stage32g(gB, Bs, 4096, k2, 0, t256);
    __builtin_amdgcn_s_setprio(1);
    #pragma unroll
    for (int i = 0; i < 4; ++i)
      #pragma unroll
      for (int j = 0; j < 4; ++j)
        acc[4 + i][j] = mfma16(a[i], b[j], acc[4 + i][j]);
    __builtin_amdgcn_s_setprio(0);
    __builtin_amdgcn_sched_barrier(0);
    if (t + 2 < KT) asm volatile("s_waitcnt vmcnt(2)" ::: "memory");
    else            asm volatile("s_waitcnt vmcnt(0)" ::: "memory");
    asm volatile("s_barrier" ::: "memory");
  }

  // ---- cross-group reduce through LDS (2 rounds of 64KB), then fused epilogue ----
  float* ex = (float*)&lds[0][0][0];
  #pragma unroll
  for (int half = 0; half < 2; ++half) {
    __syncthreads();
    if (ks == 1) {
      #pragma unroll
      for (int i = 0; i < 4; ++i)
        #pragma unroll
        for (int j = 0; j < 4; ++j)
          *(f32x4*)(ex + ((size_t)(w4 * 16 + i * 4 + j)) * 256 + lane * 4) =
              acc[half * 4 + i][j];
    }
    __syncthreads();
    if (ks == 0) {
      #pragma unroll
      for (int i = 0; i < 4; ++i)
        #pragma unroll
        for (int j = 0; j < 4; ++j) {
          const f32x4 v = *(const f32x4*)(ex + ((size_t)(w4 * 16 + i * 4 + j)) * 256 + lane * 4);
          acc[half * 4 + i][j] += v;
        }
    }
  }
  if (ks == 0) {
    const size_t rbase = (size_t)row0 + wm * 128 + quad * 4;
    const int cbase = col0 + wn * 64 + l15;
    #pragma unroll
    for (int i = 0; i < 8; ++i) {
      #pragma unroll
      for (int j = 0; j < 4; ++j) {
        const int col = cbase + j * 16;
        const float bval = bias[col];
        #pragma unroll
        for (int r = 0; r < 4; ++r) {
          const size_t row = rbase + i * 16 + r;
          out[row * 1024 + col] = acc[i][j][r] + bval + bf2f(res[row * 1024 + col]);
        }
      }
    }
  }
}

// ---------- fused causal attention v5 ----------
__global__ __launch_bounds__(256) void attn5(const unsigned short* __restrict__ qb,
                                             const unsigned short* __restrict__ kp,
                                             const unsigned short* __restrict__ vt,
                                             unsigned short* __restrict__ attnb) {
  const int lin = (blockIdx.z * 16 + blockIdx.y) * 8 + blockIdx.x;  // 512 blocks
  const int xcd = lin & 7, idx = lin >> 3;
  const int bh = xcd * 8 + (idx >> 3);
  const int xb = idx & 7;
  const int b = bh >> 4, h = bh & 15;
  const int tid = threadIdx.x, wave = tid >> 6, lane = tid & 63;
  const int l15 = lane & 15, quad = lane >> 4;
  const size_t tokbase = (size_t)b * SEQ;

  __shared__ __align__(16) unsigned short ks[64 * 64];       // [key][dim], chunk-swizzled
  __shared__ __align__(16) unsigned short vts[64 * 64];      // [dim][key], chunk-swizzled
  __shared__ __align__(16) unsigned short plds[4][32 * 64];  // per-wave P[q][key], swizzled

  const unsigned short* kbase = kp + (size_t)bh * SEQ * HDIM;
  const unsigned short* vbase = vt + (size_t)bh * HDIM * SEQ;

  for (int half = 0; half < 2; ++half) {
    const int qblk = (half == 0) ? (15 - xb) : xb;
    const int qw0 = qblk * 128 + wave * 32;

    bf16x8 qf[2][2];   // [qf][kf]: rows qw0+qf*16+l15, dims kf*32+quad*8..+8
    #pragma unroll
    for (int qfi = 0; qfi < 2; ++qfi)
      #pragma unroll
      for (int kf = 0; kf < 2; ++kf)
        qf[qfi][kf] = load8bf(qb + (tokbase + qw0 + qfi * 16 + l15) * 1024
                              + h * HDIM + kf * 32 + quad * 8);

    f32x4 o[2][4] = {};
    float lsum[2] = {0.0f, 0.0f};

    const int ntiles = qblk * 2 + 2;
    for (int kt = 0; kt < ntiles; ++kt) {
      const int k0 = kt * 64;
      __syncthreads();                       // previous tile fully consumed
      #pragma unroll
      for (int i = 0; i < 2; ++i) {          // stage K tile (8KB)
        const int cid = i * 256 + tid;
        const int r = cid >> 3, p = cid & 7, c = p ^ (r & 7);
        gload16(kbase + (size_t)(k0 + r) * HDIM + c * 8, ks + cid * 8);
      }
      #pragma unroll
      for (int i = 0; i < 2; ++i) {          // stage V^T tile (8KB)
        const int cid = i * 256 + tid;
        const int d = cid >> 3, p = cid & 7, c = p ^ (d & 7);
        gload16(vbase + (size_t)d * SEQ + k0 + c * 8, vts + cid * 8);
      }
      __syncthreads();                       // vmcnt drain -> staged data visible
      if (k0 <= qw0 + 31) {
        // ---- QK^T (swapped): s[keyf][qfi] ----
        f32x4 s[4][2] = {};
        #pragma unroll
        for (int kf = 0; kf < 2; ++kf)
          #pragma unroll
          for (int keyf = 0; keyf < 4; ++keyf) {
            const int row = keyf * 16 + l15;
            const int p = (kf * 4 + quad) ^ (row & 7);
            const bf16x8 kfr = load8bf(ks + row * 64 + p * 8);
            s[keyf][0] = mfma16(kfr, qf[0][kf], s[keyf][0]);
            s[keyf][1] = mfma16(kfr, qf[1][kf], s[keyf][1]);
          }
        // ---- fixed-max softmax + packed P store ----
        #pragma unroll
        for (int qfi = 0; qfi < 2; ++qfi) {
          const int q = qw0 + qfi * 16 + l15;
          const int qloc = qfi * 16 + l15;
          #pragma unroll
          for (int keyf = 0; keyf < 4; ++keyf) {
            unsigned int pw[4];
            #pragma unroll
            for (int r = 0; r < 4; ++r) {
              const int key = k0 + keyf * 16 + quad * 4 + r;
              float p = __builtin_amdgcn_exp2f(s[keyf][qfi][r]);
              p = (key > q) ? 0.0f : p;
              pw[r] = __builtin_bit_cast(unsigned int, p);
              lsum[qfi] += __builtin_bit_cast(float, pw[r] & 0xFFFF0000u);
            }
            u32x2 packed;
            packed.x = (pw[0] >> 16) | (pw[1] & 0xFFFF0000u);
            packed.y = (pw[2] >> 16) | (pw[3] & 0xFFFF0000u);
            const int slot = (keyf * 4 + quad) ^ ((l15 & 7) << 1);
            *(u32x2*)(&plds[wave][qloc * 64 + slot * 4]) = packed;
          }
        }
        __builtin_amdgcn_s_waitcnt(0);       // wave-local plds writes -> reads
        // ---- PV: A=P (m=q,k=key), B=V^T (n=d,k=key) ----
        #pragma unroll
        for (int kf = 0; kf < 2; ++kf) {
          bf16x8 pa[2];
          #pragma unroll
          for (int mf = 0; mf < 2; ++mf) {
            const int lq = mf * 16 + l15;
            const int c = (kf * 4 + quad) ^ (l15 & 7);
            pa[mf] = load8bf(&plds[wave][lq * 64 + c * 8]);
          }
          #pragma unroll
          for (int df = 0; df < 4; ++df) {
            const int row = df * 16 + l15;
            const int p = (kf * 4 + quad) ^ (row & 7);
            const bf16x8 vb = load8bf(vts + row * 64 + p * 8);
            o[0][df] = mfma16(pa[0], vb, o[0][df]);
            o[1][df] = mfma16(pa[1], vb, o[1][df]);
          }
        }
      }
    }
    // ---- normalize + write ----
    #pragma unroll
    for (int mf = 0; mf < 2; ++mf) {
      float l = lsum[mf];
      l += __shfl_xor(l, 16);
      l += __shfl_xor(l, 32);
      const float rl = 1.0f / l;
      #pragma unroll
      for (int r = 0; r < 4; ++r) {
        const float rv = __shfl(rl, quad * 4 + r);   // lane holding q=..+quad*4+r
        const size_t row = tokbase + qw0 + mf * 16 + quad * 4 + r;
        #pragma unroll
        for (int df = 0; df < 4; ++df)
          attnb[row * D_MODEL + h * HDIM + df * 16 + l15] = f2bf(o[mf][df][r] * rv);
      }
    }
  }
}

// ---------- host ----------
extern "C" void kernel_launch(void* const* d_in, const int* in_sizes, int n_in,
                              void* d_out, int out_size, void* d_ws, size_t ws_size,
                              hipStream_t stream) {
  const float* x    = (const float*)d_in[0];
  const float* wq   = (const float*)d_in[1];
  const float* wk   = (const float*)d_in[2];
  const float* wv   = (const float*)d_in[3];
  const float* wo   = (const float*)d_in[4];
  const float* bo   = (const float*)d_in[5];
  const float* w1   = (const float*)d_in[6];
  const float* b1   = (const float*)d_in[7];
  const float* w2   = (const float*)d_in[8];
  const float* b2   = (const float*)d_in[9];
  const float* g1   = (const float*)d_in[10];
  const float* bl1  = (const float*)d_in[11];
  const float* g2   = (const float*)d_in[12];
  const float* bl2  = (const float*)d_in[13];
  float* out = (float*)d_out;

  char* ws = (char*)d_ws;
  size_t off = 0;
  auto alloc = [&](size_t bytes) { char* p = ws + off; off += (bytes + 255) & ~(size_t)255; return p; };
  unsigned short* wqkv_t = (unsigned short*)alloc((size_t)3072 * 1024 * 2);
  unsigned short* wo_t   = (unsigned short*)alloc((size_t)1024 * 1024 * 2);
  unsigned short* w1_t   = (unsigned short*)alloc((size_t)4096 * 1024 * 2);
  unsigned short* w2_t   = (unsigned short*)alloc((size_t)1024 * 4096 * 2);
  unsigned short* h1     = (unsigned short*)alloc((size_t)NTOK * 1024 * 2);
  unsigned short* kpb    = (unsigned short*)alloc((size_t)NTOK * 1024 * 2);  // K packed
  unsigned short* vtb    = (unsigned short*)alloc((size_t)NTOK * 1024 * 2);  // V^T packed
  unsigned short* attnb  = (unsigned short*)alloc((size_t)NTOK * 1024 * 2);
  unsigned short* h2     = (unsigned short*)alloc((size_t)NTOK * 1024 * 2);
  unsigned short* ffn1   = (unsigned short*)alloc((size_t)NTOK * 4096 * 2);
  // qb aliases attnb; x1b aliases h1 (dead after QKV GEMM).
  unsigned short* qb  = attnb;
  unsigned short* x1b = h1;

  tcast_all<<<12288, 256, 0, stream>>>(wq, wk, wv, wo, w1, w2,
                                       wqkv_t, wo_t, w1_t, w2_t);
  ln_kernel<1><<<NTOK, 256, 0, stream>>>(x, g1, bl1, h1);
  // fused QKV (free-flow 256^2): 12x32 = 384 blocks
  gemm256<false, false, 0, true, true><<<dim3(12, 32), 512, 0, stream>>>(
      h1, wqkv_t, nullptr, nullptr, nullptr, qb, kpb, vtb, NTOK, 3072, 1024);
  attn5<<<dim3(SEQ / 256, NHEAD, NBATCH), 256, 0, stream>>>(qb, kpb, vtb, attnb);
  // x1 = x + attn @ wo + bo  -> bf16 x1b   (legacy 128^2)
  gemm_bt<true, false, 1, true><<<dim3(8, 64), 256, 0, stream>>>(
      attnb, wo_t, bo, x, x1b, NTOK, 1024, 1024);
  ln_kernel<0><<<NTOK, 256, 0, stream>>>(x1b, g2, bl2, h2);
  // FFN1 (free-flow 256^2): 16x32 = 512 blocks = 2 exact fill rounds
  gemm256<true, true, 0, true, false><<<dim3(16, 32), 512, 0, stream>>>(
      h2, w1_t, b1, nullptr, ffn1, nullptr, nullptr, nullptr, NTOK, 4096, 1024);
  // FFN2: in-block split-K, fused reduce+bias+residual, 8x32 = 256 blocks
  gemm_ffn2<<<dim3(8, 32), 512, 0, stream>>>(ffn1, w2_t, b2, x1b, out);
  (void)in_sizes; (void)n_in; (void)out_size; (void)ws_size;
}

// Round 9
// 445.649 us; speedup vs baseline: 4.0307x; 1.0036x over previous
//
#include <hip/hip_runtime.h>
#include <cstdint>

// ---------- types ----------
typedef __bf16 bf16x8 __attribute__((ext_vector_type(8)));
typedef float f32x4 __attribute__((ext_vector_type(4)));
typedef unsigned int u32x4 __attribute__((ext_vector_type(4)));
typedef unsigned int u32x2 __attribute__((ext_vector_type(2)));
typedef unsigned short u16x4 __attribute__((ext_vector_type(4)));

#define D_MODEL 1024
#define SEQ     2048
#define NBATCH  4
#define NHEAD   16
#define HDIM    64
#define NTOK    (NBATCH * SEQ)   // 8192
#define QSCALE  0.18033688011112042f   // 0.125 * log2(e)

__device__ __forceinline__ unsigned short f2bf(float f) {
  unsigned int u = __builtin_bit_cast(unsigned int, f);
  u += 0x7FFFu + ((u >> 16) & 1u);           // round-to-nearest-even
  return (unsigned short)(u >> 16);
}

__device__ __forceinline__ float bf2f(unsigned short s) {
  return __builtin_bit_cast(float, (unsigned int)s << 16);
}

__device__ __forceinline__ bf16x8 load8bf(const unsigned short* p) {
  return __builtin_bit_cast(bf16x8, *(const u32x4*)p);
}

__device__ __forceinline__ f32x4 mfma16(bf16x8 a, bf16x8 b, f32x4 c) {
  return __builtin_amdgcn_mfma_f32_16x16x32_bf16(a, b, c, 0, 0, 0);
}

// async global->LDS, 16B per lane; LDS dest must be waveBase + lane*16
__device__ __forceinline__ void gload16(const unsigned short* g, unsigned short* l) {
  __builtin_amdgcn_global_load_lds((__attribute__((address_space(1))) void*)g,
                                   (__attribute__((address_space(3))) void*)l, 16, 0, 0);
}

// ---------- batched transposing weight cast: out[n][k] = bf16(in[k][n]) ----------
__global__ __launch_bounds__(256) void tcast_all(const float* __restrict__ wq,
                                                 const float* __restrict__ wk,
                                                 const float* __restrict__ wv,
                                                 const float* __restrict__ wo,
                                                 const float* __restrict__ w1,
                                                 const float* __restrict__ w2,
                                                 unsigned short* __restrict__ wqkv_t,
                                                 unsigned short* __restrict__ wo_t,
                                                 unsigned short* __restrict__ w1_t,
                                                 unsigned short* __restrict__ w2_t) {
  const int id = blockIdx.x;
  const float* in; unsigned short* out; int K, N, k0, n0;
  if (id < 4096) {             // wq/wk/wv/wo: 1024x1024 each
    const int seg = id >> 10, r = id & 1023;
    in  = seg == 0 ? wq : seg == 1 ? wk : seg == 2 ? wv : wo;
    out = seg == 3 ? wo_t : wqkv_t + (size_t)seg * 1024 * 1024;
    K = 1024; N = 1024; n0 = (r & 31) * 32; k0 = (r >> 5) * 32;
  } else if (id < 8192) {      // w1: K=1024 -> N=4096
    const int r = id - 4096;
    in = w1; out = w1_t; K = 1024; N = 4096;
    n0 = (r & 127) * 32; k0 = (r >> 7) * 32;
  } else {                     // w2: K=4096 -> N=1024
    const int r = id - 8192;
    in = w2; out = w2_t; K = 4096; N = 1024;
    n0 = (r & 31) * 32; k0 = (r >> 5) * 32;
  }
  __shared__ float tile[32][33];
  const int tx = threadIdx.x & 31, ty = threadIdx.x >> 5;
  #pragma unroll
  for (int j = 0; j < 4; ++j)
    tile[ty + 8 * j][tx] = in[(size_t)(k0 + ty + 8 * j) * N + n0 + tx];
  __syncthreads();
  #pragma unroll
  for (int j = 0; j < 4; ++j)
    out[(size_t)(n0 + ty + 8 * j) * K + k0 + tx] = f2bf(tile[tx][ty + 8 * j]);
}

// ---------- layernorm (D=1024): FPIN=1 fp32 input, else bf16 input ----------
template <int FPIN>
__global__ __launch_bounds__(256) void ln_kernel(const void* __restrict__ xin,
                                                 const float* __restrict__ g,
                                                 const float* __restrict__ bb,
                                                 unsigned short* __restrict__ out) {
  const int row = blockIdx.x, tid = threadIdx.x;
  float4 xv;
  if (FPIN) {
    xv = ((const float4*)((const float*)xin + (size_t)row * D_MODEL))[tid];
  } else {
    const u16x4 bv4 = ((const u16x4*)((const unsigned short*)xin + (size_t)row * D_MODEL))[tid];
    xv.x = bf2f(bv4.x); xv.y = bf2f(bv4.y); xv.z = bf2f(bv4.z); xv.w = bf2f(bv4.w);
  }
  float s  = xv.x + xv.y + xv.z + xv.w;
  float ss = xv.x * xv.x + xv.y * xv.y + xv.z * xv.z + xv.w * xv.w;
  #pragma unroll
  for (int off = 1; off < 64; off <<= 1) { s += __shfl_xor(s, off); ss += __shfl_xor(ss, off); }
  __shared__ float red[8];
  const int wave = tid >> 6, lane = tid & 63;
  if (lane == 0) { red[wave] = s; red[4 + wave] = ss; }
  __syncthreads();
  s  = red[0] + red[1] + red[2] + red[3];
  ss = red[4] + red[5] + red[6] + red[7];
  const float mu   = s * (1.0f / D_MODEL);
  const float var  = ss * (1.0f / D_MODEL) - mu * mu;
  const float rstd = rsqrtf(var + 1e-5f);
  const float4 gv = ((const float4*)g)[tid];
  const float4 bv = ((const float4*)bb)[tid];
  u16x4 o;
  o.x = f2bf((xv.x - mu) * rstd * gv.x + bv.x);
  o.y = f2bf((xv.y - mu) * rstd * gv.y + bv.y);
  o.z = f2bf((xv.z - mu) * rstd * gv.z + bv.z);
  o.w = f2bf((xv.w - mu) * rstd * gv.w + bv.w);
  *(u16x4*)(out + (size_t)row * D_MODEL + tid * 4) = o;
}

// ---------- GEMM (legacy 128x128, used for WO): C = A * Bt^T ----------
template <bool BIAS, bool RELU, int RES, bool OBF>
__global__ __launch_bounds__(256) void gemm_bt(const unsigned short* __restrict__ A,
                                               const unsigned short* __restrict__ Bt,
                                               const float* __restrict__ bias,
                                               const void* __restrict__ res,
                                               void* __restrict__ out,
                                               int M, int N, int K) {
  __shared__ __align__(16) unsigned short As[128 * 64];
  __shared__ __align__(16) unsigned short Bs[128 * 64];
  const int tid  = threadIdx.x;
  const int lin = blockIdx.y * gridDim.x + blockIdx.x;   // gridDim.y == 64 always
  const int xcd = lin & 7, idx = lin >> 3;
  const int by = xcd * 8 + (idx & 7);
  const int bx = idx >> 3;
  const int row0 = by * 128, col0 = bx * 128;
  const int wave = tid >> 6, lane = tid & 63;
  const int wm = wave >> 1, wn = wave & 1;
  const int l15 = lane & 15, quad = lane >> 4;
  f32x4 acc[4][4] = {};

  const int tr = tid >> 3;                        // base row 0..31
  const int tc = (tid & 7) ^ (tr & 7);            // swizzled source chunk
  const unsigned short* gA = A  + (size_t)(row0 + tr) * K + tc * 8;
  const unsigned short* gB = Bt + (size_t)(col0 + tr) * K + tc * 8;

  const int rowA = (wm * 64 + l15) * 64;
  const int rowB = (wn * 64 + l15) * 64;
  const int swz0 = (quad ^ (l15 & 7)) * 8;
  const int swz1 = ((4 + quad) ^ (l15 & 7)) * 8;

  for (int k0 = 0; k0 < K; k0 += 64) {
    #pragma unroll
    for (int i = 0; i < 4; ++i) {
      gload16(gA + (size_t)(i * 32) * K + k0, As + (i * 256 + tid) * 8);
      gload16(gB + (size_t)(i * 32) * K + k0, Bs + (i * 256 + tid) * 8);
    }
    __syncthreads();
    #pragma unroll
    for (int kf = 0; kf < 2; ++kf) {
      const int swz = kf ? swz1 : swz0;
      bf16x8 af[4], bfr[4];
      #pragma unroll
      for (int t = 0; t < 4; ++t) {
        af[t]  = load8bf(As + rowA + t * 1024 + swz);
        bfr[t] = load8bf(Bs + rowB + t * 1024 + swz);
      }
      #pragma unroll
      for (int i = 0; i < 4; ++i)
        #pragma unroll
        for (int j = 0; j < 4; ++j)
          acc[i][j] = mfma16(af[i], bfr[j], acc[i][j]);
    }
    __syncthreads();
  }

  const size_t rbase = (size_t)row0 + wm * 64 + quad * 4;
  const int cbase = col0 + wn * 64 + l15;
  #pragma unroll
  for (int i = 0; i < 4; ++i) {
    #pragma unroll
    for (int j = 0; j < 4; ++j) {
      const int col = cbase + j * 16;
      const float bval = BIAS ? bias[col] : 0.0f;
      #pragma unroll
      for (int r = 0; r < 4; ++r) {
        const size_t row = rbase + i * 16 + r;
        float v = acc[i][j][r];
        if (BIAS) v += bval;
        if (RELU) v = fmaxf(v, 0.0f);
        if (RES == 1) v += ((const float*)res)[row * N + col];
        if (RES == 2) v += bf2f(((const unsigned short*)res)[row * N + col]);
        if (OBF)  ((unsigned short*)out)[row * N + col] = f2bf(v);
        else      ((float*)out)[row * N + col] = v;
      }
    }
  }
}

// ---------- staging helper: one 128-row x 64-col half-tile, 512 threads ----------
__device__ __forceinline__ void stage_half_512(const unsigned short* __restrict__ src,
                                               unsigned short* dst, int ld, int k0,
                                               int h, int tid) {
  #pragma unroll
  for (int l = 0; l < 2; ++l) {
    const int cid = l * 512 + tid;
    const int r = cid >> 3, p = cid & 7, c = p ^ (r & 7);
    gload16(src + (size_t)(h * 128 + r) * ld + k0 + c * 8, dst + h * 8192 + cid * 8);
  }
}

// ---------- 256x256 free-flow GEMM, BK=64 ----------
// 2 barriers per K-tile; mid barrier after Q-half-1 guarantees all waves' B
// ds_reads done (via each wave's MFMA lgkm wait + sched_barrier pin) before
// B(t+2) staging overwrites that region. End barrier after counted vmcnt(4).
template <bool BIAS, bool RELU, int RES, bool OBF, bool QKV>
__global__ __launch_bounds__(512, 2) void gemm256(const unsigned short* __restrict__ A,
                                                  const unsigned short* __restrict__ Bt,
                                                  const float* __restrict__ bias,
                                                  const void* __restrict__ res,
                                                  void* __restrict__ out,
                                                  unsigned short* __restrict__ qb,
                                                  unsigned short* __restrict__ kp,
                                                  unsigned short* __restrict__ vt,
                                                  int M, int N, int K) {
  __shared__ __align__(16) unsigned short lds[2][32768];  // [buf][ A 16384sh | B 16384sh ]
  const int tid = threadIdx.x;
  const int lin = blockIdx.y * gridDim.x + blockIdx.x;    // gridDim.y == 32 (M = 8192)
  const int xcd = lin & 7, idx = lin >> 3;
  const int by = xcd * 4 + (idx & 3);
  const int bx = idx >> 2;
  const int row0 = by * 256, col0 = bx * 256;
  const int wave = tid >> 6, lane = tid & 63;
  const int wm = wave >> 2, wn = wave & 3;                // 2 x 4 waves, 128x64 each
  const int l15 = lane & 15, quad = lane >> 4;
  const int swz0 = (quad ^ (l15 & 7)) * 8;
  const int swz1 = ((4 + quad) ^ (l15 & 7)) * 8;

  const unsigned short* gA = A  + (size_t)row0 * K;
  const unsigned short* gB = Bt + (size_t)col0 * K;

  unsigned short* As0 = &lds[0][0];
  unsigned short* Bs0 = &lds[0][16384];
  unsigned short* As1 = &lds[1][0];
  unsigned short* Bs1 = &lds[1][16384];

  f32x4 acc[8][4] = {};
  const int KT = K >> 6;

  // ---- prologue: tile0 (A+B) -> buf0; tile1 B halves -> buf1 ----
  stage_half_512(gA, As0, K, 0, 0, tid);
  stage_half_512(gA, As0, K, 0, 1, tid);
  stage_half_512(gB, Bs0, K, 0, 0, tid);
  stage_half_512(gB, Bs0, K, 0, 1, tid);
  if (KT > 1) {
    stage_half_512(gB, Bs1, K, 64, 0, tid);
    stage_half_512(gB, Bs1, K, 64, 1, tid);
    asm volatile("s_waitcnt vmcnt(4)" ::: "memory");
  } else {
    asm volatile("s_waitcnt vmcnt(0)" ::: "memory");
  }
  asm volatile("s_barrier" ::: "memory");

  for (int t = 0; t < KT; ++t) {
    unsigned short* As  = (t & 1) ? As1 : As0;
    unsigned short* Bs  = (t & 1) ? Bs1 : Bs0;
    unsigned short* Asn = (t & 1) ? As0 : As1;
    const int k1 = (t + 1) << 6, k2 = (t + 2) << 6;
    bf16x8 a0[2][4], b01[2][2], b23[2][2];

    // ===== half 1: read A-group0 (8) + all B (8); stage t+1.A; Q00 + Q01 =====
    #pragma unroll
    for (int i = 0; i < 4; ++i) {
      const unsigned short* ap = As + (wm * 128 + i * 16 + l15) * 64;
      a0[0][i] = load8bf(ap + swz0);
      a0[1][i] = load8bf(ap + swz1);
    }
    #pragma unroll
    for (int j = 0; j < 2; ++j) {
      const unsigned short* bp = Bs + (wn * 64 + j * 16 + l15) * 64;
      b01[0][j] = load8bf(bp + swz0);
      b01[1][j] = load8bf(bp + swz1);
      const unsigned short* bp2 = Bs + (wn * 64 + 32 + j * 16 + l15) * 64;
      b23[0][j] = load8bf(bp2 + swz0);
      b23[1][j] = load8bf(bp2 + swz1);
    }
    if (t + 1 < KT) {
      stage_half_512(gA, Asn, K, k1, 0, tid);
      stage_half_512(gA, Asn, K, k1, 1, tid);
    }
    __builtin_amdgcn_s_setprio(1);
    #pragma unroll
    for (int kf = 0; kf < 2; ++kf)
      #pragma unroll
      for (int i = 0; i < 4; ++i)
        #pragma unroll
        for (int j = 0; j < 2; ++j)
          acc[i][j] = mfma16(a0[kf][i], b01[kf][j], acc[i][j]);
    #pragma unroll
    for (int kf = 0; kf < 2; ++kf)
      #pragma unroll
      for (int i = 0; i < 4; ++i)
        #pragma unroll
        for (int j = 0; j < 2; ++j)
          acc[i][2 + j] = mfma16(a0[kf][i], b23[kf][j], acc[i][2 + j]);
    __builtin_amdgcn_s_setprio(0);
    __builtin_amdgcn_sched_barrier(0);
    asm volatile("s_barrier" ::: "memory");   // all B reads of tile t complete

    // ===== half 2: read A-group1 (reuse regs); stage t+2.B (cur buf); Q11 + Q10 =====
    #pragma unroll
    for (int i = 0; i < 4; ++i) {
      const unsigned short* ap = As + (wm * 128 + 64 + i * 16 + l15) * 64;
      a0[0][i] = load8bf(ap + swz0);
      a0[1][i] = load8bf(ap + swz1);
    }
    if (t + 2 < KT) {
      stage_half_512(gB, Bs, K, k2, 0, tid);
      stage_half_512(gB, Bs, K, k2, 1, tid);
    }
    __builtin_amdgcn_s_setprio(1);
    #pragma unroll
    for (int kf = 0; kf < 2; ++kf)
      #pragma unroll
      for (int i = 0; i < 4; ++i)
        #pragma unroll
        for (int j = 0; j < 2; ++j)
          acc[4 + i][2 + j] = mfma16(a0[kf][i], b23[kf][j], acc[4 + i][2 + j]);
    #pragma unroll
    for (int kf = 0; kf < 2; ++kf)
      #pragma unroll
      for (int i = 0; i < 4; ++i)
        #pragma unroll
        for (int j = 0; j < 2; ++j)
          acc[4 + i][j] = mfma16(a0[kf][i], b01[kf][j], acc[4 + i][j]);
    __builtin_amdgcn_s_setprio(0);
    __builtin_amdgcn_sched_barrier(0);
    if (t + 2 < KT) asm volatile("s_waitcnt vmcnt(4)" ::: "memory");
    else            asm volatile("s_waitcnt vmcnt(0)" ::: "memory");
    asm volatile("s_barrier" ::: "memory");
  }

  // ---- epilogue ----
  const size_t rbase = (size_t)row0 + wm * 128 + quad * 4;
  const int cbase = col0 + wn * 64 + l15;
  if (QKV) {
    const int sec = col0 >> 10;           // block-uniform (256 | 1024): 0=Q, 1=K, 2=V
    #pragma unroll
    for (int i = 0; i < 8; ++i) {
      #pragma unroll
      for (int j = 0; j < 4; ++j) {
        const int col = cbase + j * 16;
        if (sec == 0) {
          #pragma unroll
          for (int r = 0; r < 4; ++r) {
            const size_t row = rbase + i * 16 + r;
            qb[row * 1024 + col] = f2bf(acc[i][j][r] * QSCALE);
          }
        } else if (sec == 1) {
          const int c2 = col - 1024, hh = c2 >> 6, d = c2 & 63;
          #pragma unroll
          for (int r = 0; r < 4; ++r) {
            const size_t row = rbase + i * 16 + r;
            const int bb = (int)(row >> 11), tt = (int)(row & 2047);
            kp[(((size_t)(bb * 16 + hh)) * SEQ + tt) * 64 + d] = f2bf(acc[i][j][r]);
          }
        } else {
          const int c2 = col - 2048, hh = c2 >> 6, d = c2 & 63;
          const size_t t0 = rbase + i * 16;
          const int bb = (int)(t0 >> 11);
          u16x4 pk;
          #pragma unroll
          for (int r = 0; r < 4; ++r) pk[r] = f2bf(acc[i][j][r]);
          *(u16x4*)(vt + ((size_t)(bb * 16 + hh) * 64 + d) * SEQ + (t0 & 2047)) = pk;
        }
      }
    }
  } else {
    #pragma unroll
    for (int i = 0; i < 8; ++i) {
      #pragma unroll
      for (int j = 0; j < 4; ++j) {
        const int col = cbase + j * 16;
        const float bval = BIAS ? bias[col] : 0.0f;
        #pragma unroll
        for (int r = 0; r < 4; ++r) {
          const size_t row = rbase + i * 16 + r;
          float v = acc[i][j][r];
          if (BIAS) v += bval;
          if (RELU) v = fmaxf(v, 0.0f);
          if (RES == 1) v += ((const float*)res)[row * N + col];
          if (RES == 2) v += bf2f(((const unsigned short*)res)[row * N + col]);
          if (OBF)  ((unsigned short*)out)[row * N + col] = f2bf(v);
          else      ((float*)out)[row * N + col] = v;
        }
      }
    }
  }
  (void)M;
}

// ---------- BK=32 staging for FFN2 groups: 128 rows x 32 cols (8KB), 256 thr ----------
__device__ __forceinline__ void stage32g(const unsigned short* __restrict__ src,
                                         unsigned short* dst, int ld, int k0,
                                         int h128, int t256) {
  #pragma unroll
  for (int l = 0; l < 2; ++l) {
    const int cid = l * 256 + t256;     // 0..511
    const int L = cid >> 3;             // line 0..63
    const int p = cid & 7;
    const int c = p ^ (L & 7);
    const int row = h128 * 128 + L * 2 + (c >> 2);
    gload16(src + (size_t)row * ld + k0 + (c & 3) * 8, dst + h128 * 4096 + cid * 8);
  }
}

__device__ __forceinline__ bf16x8 frag32(const unsigned short* tile, int r0,
                                         int l15, int quad) {
  const int row = r0 + l15;
  const int L = row >> 1;
  const int p = ((row & 1) * 4 + quad) ^ (L & 7);
  return load8bf(tile + L * 64 + p * 8);
}

// ---------- FFN2: 256x128 tile, IN-BLOCK split-K=2, fused reduce+bias+residual ----------
__global__ __launch_bounds__(512, 2) void gemm_ffn2(const unsigned short* __restrict__ A,
                                                    const unsigned short* __restrict__ Bt,
                                                    const float* __restrict__ bias,
                                                    const unsigned short* __restrict__ res,
                                                    float* __restrict__ out) {
  __shared__ __align__(16) unsigned short lds[2][2][12288]; // [grp][buf][A 8192 | B 4096]
  const int tid = threadIdx.x;
  const int lin = blockIdx.y * gridDim.x + blockIdx.x;      // 8 x 32 = 256 blocks
  const int xcd = lin & 7, idx = lin >> 3;
  const int by = xcd * 4 + (idx & 3);
  const int bx = idx >> 2;
  const int row0 = by * 256, col0 = bx * 128;
  const int wave = tid >> 6, lane = tid & 63;
  const int ks = wave >> 2;                                 // K-group 0/1
  const int w4 = wave & 3;
  const int wm = w4 >> 1, wn = w4 & 1;                      // 2x2, wave tile 128x64
  const int l15 = lane & 15, quad = lane >> 4;
  const int t256 = tid & 255;                               // group-local thread

  const unsigned short* gA = A  + (size_t)row0 * 4096 + ks * 2048;
  const unsigned short* gB = Bt + (size_t)col0 * 4096 + ks * 2048;

  unsigned short* As0 = &lds[ks][0][0];
  unsigned short* Bs0 = &lds[ks][0][8192];
  unsigned short* As1 = &lds[ks][1][0];
  unsigned short* Bs1 = &lds[ks][1][8192];

  f32x4 acc[8][4] = {};
  const int KT = 64;                                        // 2048 / 32

  // ---- prologue: tile0 A(2 halves)+B -> buf0; tile1 B -> buf1 ----
  stage32g(gA, As0, 4096, 0, 0, t256);
  stage32g(gA, As0, 4096, 0, 1, t256);
  stage32g(gB, Bs0, 4096, 0, 0, t256);
  stage32g(gB, Bs1, 4096, 32, 0, t256);
  asm volatile("s_waitcnt vmcnt(2)" ::: "memory");          // tile0 done, tile1.B in flight
  asm volatile("s_barrier" ::: "memory");

  for (int t = 0; t < KT; ++t) {
    unsigned short* As  = (t & 1) ? As1 : As0;
    unsigned short* Bs  = (t & 1) ? Bs1 : Bs0;
    unsigned short* Asn = (t & 1) ? As0 : As1;
    const int k1 = (t + 1) << 5, k2 = (t + 2) << 5;
    bf16x8 a[4], b[4];

    // ===== P1: read all B (4) + a[0..3]; stage A(t+1); MFMA top =====
    #pragma unroll
    for (int j = 0; j < 4; ++j) b[j] = frag32(Bs, wn * 64 + j * 16, l15, quad);
    #pragma unroll
    for (int i = 0; i < 4; ++i) a[i] = frag32(As, wm * 128 + i * 16, l15, quad);
    if (t + 1 < KT) {
      stage32g(gA, Asn, 4096, k1, 0, t256);
      stage32g(gA, Asn, 4096, k1, 1, t256);
    }
    __builtin_amdgcn_s_setprio(1);
    #pragma unroll
    for (int i = 0; i < 4; ++i)
      #pragma unroll
      for (int j = 0; j < 4; ++j)
        acc[i][j] = mfma16(a[i], b[j], acc[i][j]);
    __builtin_amdgcn_s_setprio(0);
    __builtin_amdgcn_sched_barrier(0);
    asm volatile("s_barrier" ::: "memory");   // all B reads of tile t complete

    // ===== P2: read a[4..7]; stage B(t+2) -> cur-B (consumed in P1); MFMA bottom =====
    #pragma unroll
    for (int i = 0; i < 4; ++i) a[i] = frag32(As, wm * 128 + 64 + i * 16, l15, quad);
    if (t + 2 < KT) stage32g(gB, Bs, 4096, k2, 0, t256);
    __builtin_amdgcn_s_setprio(1);
    #pragma unroll
    for (int i = 0; i < 4; ++i)
      #pragma unroll
      for (int j = 0; j < 4; ++j)
        acc[4 + i][j] = mfma16(a[i], b[j], acc[4 + i][j]);
    __builtin_amdgcn_s_setprio(0);
    __builtin_amdgcn_sched_barrier(0);
    if (t + 2 < KT) asm volatile("s_waitcnt vmcnt(2)" ::: "memory");
    else            asm volatile("s_waitcnt vmcnt(0)" ::: "memory");
    asm volatile("s_barrier" ::: "memory");
  }

  // ---- cross-group reduce through LDS (2 rounds of 64KB), then fused epilogue ----
  float* ex = (float*)&lds[0][0][0];
  #pragma unroll
  for (int half = 0; half < 2; ++half) {
    __syncthreads();
    if (ks == 1) {
      #pragma unroll
      for (int i = 0; i < 4; ++i)
        #pragma unroll
        for (int j = 0; j < 4; ++j)
          *(f32x4*)(ex + ((size_t)(w4 * 16 + i * 4 + j)) * 256 + lane * 4) =
              acc[half * 4 + i][j];
    }
    __syncthreads();
    if (ks == 0) {
      #pragma unroll
      for (int i = 0; i < 4; ++i)
        #pragma unroll
        for (int j = 0; j < 4; ++j) {
          const f32x4 v = *(const f32x4*)(ex + ((size_t)(w4 * 16 + i * 4 + j)) * 256 + lane * 4);
          acc[half * 4 + i][j] += v;
        }
    }
  }
  if (ks == 0) {
    const size_t rbase = (size_t)row0 + wm * 128 + quad * 4;
    const int cbase = col0 + wn * 64 + l15;
    #pragma unroll
    for (int i = 0; i < 8; ++i) {
      #pragma unroll
      for (int j = 0; j < 4; ++j) {
        const int col = cbase + j * 16;
        const float bval = bias[col];
        #pragma unroll
        for (int r = 0; r < 4; ++r) {
          const size_t row = rbase + i * 16 + r;
          out[row * 1024 + col] = acc[i][j][r] + bval + bf2f(res[row * 1024 + col]);
        }
      }
    }
  }
}

// ---------- fused causal attention v6: double-buffered K/V prefetch ----------
// Per tile: issue stage(kt+1) into other buffer BEFORE compute on buf[kt&1];
// drain (vmcnt(0)) lands AFTER compute -> staging latency hides under
// QK^T/softmax/PV. Race ledger: stage(kt+1) overwrites the buffer last read in
// iter kt-1; those reads completed before kt-1's end barrier (each ds_read is
// consumed by an MFMA whose lgkm wait forces retirement before MFMA issue;
// sched_barrier(0) pins all MFMAs before the barrier). plds sync is lgkm-only
// (wave-local) so the in-flight prefetch is not drained mid-tile.
__global__ __launch_bounds__(256) void attn5(const unsigned short* __restrict__ qb,
                                             const unsigned short* __restrict__ kp,
                                             const unsigned short* __restrict__ vt,
                                             unsigned short* __restrict__ attnb) {
  const int lin = (blockIdx.z * 16 + blockIdx.y) * 8 + blockIdx.x;  // 512 blocks
  const int xcd = lin & 7, idx = lin >> 3;
  const int bh = xcd * 8 + (idx >> 3);
  const int xb = idx & 7;
  const int b = bh >> 4, h = bh & 15;
  const int tid = threadIdx.x, wave = tid >> 6, lane = tid & 63;
  const int l15 = lane & 15, quad = lane >> 4;
  const size_t tokbase = (size_t)b * SEQ;

  __shared__ __align__(16) unsigned short ks[2][64 * 64];    // [buf][key][dim], swizzled
  __shared__ __align__(16) unsigned short vts[2][64 * 64];   // [buf][dim][key], swizzled
  __shared__ __align__(16) unsigned short plds[4][32 * 64];  // per-wave P[q][key], swizzled

  const unsigned short* kbase = kp + (size_t)bh * SEQ * HDIM;
  const unsigned short* vbase = vt + (size_t)bh * HDIM * SEQ;

  for (int half = 0; half < 2; ++half) {
    const int qblk = (half == 0) ? (15 - xb) : xb;
    const int qw0 = qblk * 128 + wave * 32;

    bf16x8 qf[2][2];   // [qf][kf]: rows qw0+qf*16+l15, dims kf*32+quad*8..+8
    #pragma unroll
    for (int qfi = 0; qfi < 2; ++qfi)
      #pragma unroll
      for (int kf = 0; kf < 2; ++kf)
        qf[qfi][kf] = load8bf(qb + (tokbase + qw0 + qfi * 16 + l15) * 1024
                              + h * HDIM + kf * 32 + quad * 8);

    f32x4 o[2][4] = {};
    float lsum[2] = {0.0f, 0.0f};

    const int ntiles = qblk * 2 + 2;

    // ---- prologue: stage tile 0 -> buf0, full drain ----
    {
      #pragma unroll
      for (int i = 0; i < 2; ++i) {
        const int cid = i * 256 + tid;
        const int r = cid >> 3, p = cid & 7, c = p ^ (r & 7);
        gload16(kbase + (size_t)r * HDIM + c * 8, &ks[0][cid * 8]);
      }
      #pragma unroll
      for (int i = 0; i < 2; ++i) {
        const int cid = i * 256 + tid;
        const int d = cid >> 3, p = cid & 7, c = p ^ (d & 7);
        gload16(vbase + (size_t)d * SEQ + c * 8, &vts[0][cid * 8]);
      }
      asm volatile("s_waitcnt vmcnt(0)" ::: "memory");
      asm volatile("s_barrier" ::: "memory");
    }

    for (int kt = 0; kt < ntiles; ++kt) {
      const int k0 = kt * 64;
      // ---- issue prefetch of tile kt+1 into the other buffer ----
      if (kt + 1 < ntiles) {
        const int kn = (kt + 1) * 64;
        const int nb = (kt + 1) & 1;
        #pragma unroll
        for (int i = 0; i < 2; ++i) {
          const int cid = i * 256 + tid;
          const int r = cid >> 3, p = cid & 7, c = p ^ (r & 7);
          gload16(kbase + (size_t)(kn + r) * HDIM + c * 8, &ks[nb][cid * 8]);
        }
        #pragma unroll
        for (int i = 0; i < 2; ++i) {
          const int cid = i * 256 + tid;
          const int d = cid >> 3, p = cid & 7, c = p ^ (d & 7);
          gload16(vbase + (size_t)d * SEQ + kn + c * 8, &vts[nb][cid * 8]);
        }
      }
      if (k0 <= qw0 + 31) {
        const unsigned short* ksb  = ks[kt & 1];
        const unsigned short* vtsb = vts[kt & 1];
        // ---- QK^T (swapped): s[keyf][qfi] ----
        f32x4 s[4][2] = {};
        #pragma unroll
        for (int kf = 0; kf < 2; ++kf)
          #pragma unroll
          for (int keyf = 0; keyf < 4; ++keyf) {
            const int row = keyf * 16 + l15;
            const int p = (kf * 4 + quad) ^ (row & 7);
            const bf16x8 kfr = load8bf(ksb + row * 64 + p * 8);
            s[keyf][0] = mfma16(kfr, qf[0][kf], s[keyf][0]);
            s[keyf][1] = mfma16(kfr, qf[1][kf], s[keyf][1]);
          }
        // ---- fixed-max softmax + packed P store ----
        #pragma unroll
        for (int qfi = 0; qfi < 2; ++qfi) {
          const int q = qw0 + qfi * 16 + l15;
          const int qloc = qfi * 16 + l15;
          #pragma unroll
          for (int keyf = 0; keyf < 4; ++keyf) {
            unsigned int pw[4];
            #pragma unroll
            for (int r = 0; r < 4; ++r) {
              const int key = k0 + keyf * 16 + quad * 4 + r;
              float p = __builtin_amdgcn_exp2f(s[keyf][qfi][r]);
              p = (key > q) ? 0.0f : p;
              pw[r] = __builtin_bit_cast(unsigned int, p);
              lsum[qfi] += __builtin_bit_cast(float, pw[r] & 0xFFFF0000u);
            }
            u32x2 packed;
            packed.x = (pw[0] >> 16) | (pw[1] & 0xFFFF0000u);
            packed.y = (pw[2] >> 16) | (pw[3] & 0xFFFF0000u);
            const int slot = (keyf * 4 + quad) ^ ((l15 & 7) << 1);
            *(u32x2*)(&plds[wave][qloc * 64 + slot * 4]) = packed;
          }
        }
        // wave-local plds writes -> reads: lgkm only (keep prefetch in flight)
        asm volatile("s_waitcnt lgkmcnt(0)" ::: "memory");
        __builtin_amdgcn_sched_barrier(0);
        // ---- PV: A=P (m=q,k=key), B=V^T (n=d,k=key) ----
        #pragma unroll
        for (int kf = 0; kf < 2; ++kf) {
          bf16x8 pa[2];
          #pragma unroll
          for (int mf = 0; mf < 2; ++mf) {
            const int lq = mf * 16 + l15;
            const int c = (kf * 4 + quad) ^ (l15 & 7);
            pa[mf] = load8bf(&plds[wave][lq * 64 + c * 8]);
          }
          #pragma unroll
          for (int df = 0; df < 4; ++df) {
            const int row = df * 16 + l15;
            const int p = (kf * 4 + quad) ^ (row & 7);
            const bf16x8 vb = load8bf(vtsb + row * 64 + p * 8);
            o[0][df] = mfma16(pa[0], vb, o[0][df]);
            o[1][df] = mfma16(pa[1], vb, o[1][df]);
          }
        }
      }
      // ---- drain prefetch (overlapped with compute above) + rendezvous ----
      __builtin_amdgcn_sched_barrier(0);
      asm volatile("s_waitcnt vmcnt(0)" ::: "memory");
      asm volatile("s_barrier" ::: "memory");
    }
    // ---- normalize + write ----
    #pragma unroll
    for (int mf = 0; mf < 2; ++mf) {
      float l = lsum[mf];
      l += __shfl_xor(l, 16);
      l += __shfl_xor(l, 32);
      const float rl = 1.0f / l;
      #pragma unroll
      for (int r = 0; r < 4; ++r) {
        const float rv = __shfl(rl, quad * 4 + r);   // lane holding q=..+quad*4+r
        const size_t row = tokbase + qw0 + mf * 16 + quad * 4 + r;
        #pragma unroll
        for (int df = 0; df < 4; ++df)
          attnb[row * D_MODEL + h * HDIM + df * 16 + l15] = f2bf(o[mf][df][r] * rv);
      }
    }
  }
}

// ---------- host ----------
extern "C" void kernel_launch(void* const* d_in, const int* in_sizes, int n_in,
                              void* d_out, int out_size, void* d_ws, size_t ws_size,
                              hipStream_t stream) {
  const float* x    = (const float*)d_in[0];
  const float* wq   = (const float*)d_in[1];
  const float* wk   = (const float*)d_in[2];
  const float* wv   = (const float*)d_in[3];
  const float* wo   = (const float*)d_in[4];
  const float* bo   = (const float*)d_in[5];
  const float* w1   = (const float*)d_in[6];
  const float* b1   = (const float*)d_in[7];
  const float* w2   = (const float*)d_in[8];
  const float* b2   = (const float*)d_in[9];
  const float* g1   = (const float*)d_in[10];
  const float* bl1  = (const float*)d_in[11];
  const float* g2   = (const float*)d_in[12];
  const float* bl2  = (const float*)d_in[13];
  float* out = (float*)d_out;

  char* ws = (char*)d_ws;
  size_t off = 0;
  auto alloc = [&](size_t bytes) { char* p = ws + off; off += (bytes + 255) & ~(size_t)255; return p; };
  unsigned short* wqkv_t = (unsigned short*)alloc((size_t)3072 * 1024 * 2);
  unsigned short* wo_t   = (unsigned short*)alloc((size_t)1024 * 1024 * 2);
  unsigned short* w1_t   = (unsigned short*)alloc((size_t)4096 * 1024 * 2);
  unsigned short* w2_t   = (unsigned short*)alloc((size_t)1024 * 4096 * 2);
  unsigned short* h1     = (unsigned short*)alloc((size_t)NTOK * 1024 * 2);
  unsigned short* kpb    = (unsigned short*)alloc((size_t)NTOK * 1024 * 2);  // K packed
  unsigned short* vtb    = (unsigned short*)alloc((size_t)NTOK * 1024 * 2);  // V^T packed
  unsigned short* attnb  = (unsigned short*)alloc((size_t)NTOK * 1024 * 2);
  unsigned short* h2     = (unsigned short*)alloc((size_t)NTOK * 1024 * 2);
  unsigned short* ffn1   = (unsigned short*)alloc((size_t)NTOK * 4096 * 2);
  // qb aliases attnb; x1b aliases h1 (dead after QKV GEMM).
  unsigned short* qb  = attnb;
  unsigned short* x1b = h1;

  tcast_all<<<12288, 256, 0, stream>>>(wq, wk, wv, wo, w1, w2,
                                       wqkv_t, wo_t, w1_t, w2_t);
  ln_kernel<1><<<NTOK, 256, 0, stream>>>(x, g1, bl1, h1);
  // fused QKV (free-flow 256^2): 12x32 = 384 blocks
  gemm256<false, false, 0, true, true><<<dim3(12, 32), 512, 0, stream>>>(
      h1, wqkv_t, nullptr, nullptr, nullptr, qb, kpb, vtb, NTOK, 3072, 1024);
  attn5<<<dim3(SEQ / 256, NHEAD, NBATCH), 256, 0, stream>>>(qb, kpb, vtb, attnb);
  // x1 = x + attn @ wo + bo  -> bf16 x1b   (legacy 128^2)
  gemm_bt<true, false, 1, true><<<dim3(8, 64), 256, 0, stream>>>(
      attnb, wo_t, bo, x, x1b, NTOK, 1024, 1024);
  ln_kernel<0><<<NTOK, 256, 0, stream>>>(x1b, g2, bl2, h2);
  // FFN1 (free-flow 256^2): 16x32 = 512 blocks = 2 exact fill rounds
  gemm256<true, true, 0, true, false><<<dim3(16, 32), 512, 0, stream>>>(
      h2, w1_t, b1, nullptr, ffn1, nullptr, nullptr, nullptr, NTOK, 4096, 1024);
  // FFN2: in-block split-K, fused reduce+bias+residual, 8x32 = 256 blocks
  gemm_ffn2<<<dim3(8, 32), 512, 0, stream>>>(ffn1, w2_t, b2, x1b, out);
  (void)in_sizes; (void)n_in; (void)out_size; (void)ws_size;
}